// Round 6
// baseline (260.072 us; speedup 1.0000x reference)
//
#include <hip/hip_runtime.h>

#define B_ 4
#define C_ 256
#define N_ 4096
#define D_ 64

typedef __bf16 bf16x8 __attribute__((ext_vector_type(8)));
typedef float floatx4 __attribute__((ext_vector_type(4)));
typedef unsigned short ushort8v __attribute__((ext_vector_type(8)));
typedef unsigned short ushort4v __attribute__((ext_vector_type(4)));
typedef unsigned short ushort2v __attribute__((ext_vector_type(2)));

static __device__ __forceinline__ unsigned short f2bf(float f) {
    unsigned int u = __builtin_bit_cast(unsigned int, f);
    u += 0x7fffu + ((u >> 16) & 1u);   // RNE
    return (unsigned short)(u >> 16);
}
static __device__ __forceinline__ float bf2f(unsigned short h) {
    unsigned int u = ((unsigned int)h) << 16;
    return __builtin_bit_cast(float, u);
}
// HW packed f32x2 -> bf16x2 (RNE), 1 VALU op
static __device__ __forceinline__ unsigned int cvt_pk_bf16(float lo, float hi) {
    unsigned int d;
    asm("v_cvt_pk_bf16_f32 %0, %1, %2" : "=v"(d) : "v"(lo), "v"(hi));
    return d;
}

// async global->LDS DMA, 16B/lane, dst = wave-uniform base + lane*16
#define GLOAD16(gp, lp)                                                      \
    __builtin_amdgcn_global_load_lds(                                        \
        (const __attribute__((address_space(1))) void*)(gp),                 \
        (__attribute__((address_space(3))) void*)(lp), 16, 0, 0)

// ---------------------------------------------------------------------------
// MFMA projection. A-frags converted in-block from fp32 W (convert_w kernel
// and WbfA intermediate eliminated — one less dispatch). Also zeroes the
// flash/combine flags (stream-ordered before flash).
// ---------------------------------------------------------------------------
__global__ __launch_bounds__(256, 3) void proj_kernel(
    const float* __restrict__ x,
    const float* __restrict__ Wq, const float* __restrict__ Wk,
    const float* __restrict__ Wv,
    const float* __restrict__ bq, const float* __restrict__ bk,
    const float* __restrict__ bv,
    unsigned short* __restrict__ Qg, unsigned short* __restrict__ Kg,
    unsigned short* __restrict__ Vg, int* __restrict__ flags)
{
    __shared__ __align__(16) unsigned short smem[64 * 264];  // 33792 B
    unsigned short* xs = smem;          // x tile, swizzled [n][264]
    unsigned short* Lt = smem;          // epilogue tile [128][72] (union)

    const int n0 = blockIdx.x * 64;
    const int f0 = blockIdx.y * 128;
    const int b  = blockIdx.z;
    const int t  = threadIdx.x;
    const int w  = t >> 6;
    const int lane = t & 63;
    const int g  = lane >> 4;
    const int m  = lane & 15;

    // zero combine flags (one block per b)
    if (blockIdx.x == 0 && blockIdx.y == 0 && t < 32)
        flags[b * 32 + t] = 0;

#pragma unroll
    for (int k = 0; k < 8; ++k) {
        int e  = t + 256 * k;           // 0..2047
        int cp = e >> 4;                // 0..127
        int c  = 2 * cp;
        int n4 = (e & 15) * 4;
        float4 v0 = *(const float4*)(x + ((size_t)b*C_ + c    )*N_ + n0 + n4);
        float4 v1 = *(const float4*)(x + ((size_t)b*C_ + c + 1)*N_ + n0 + n4);
        float a0[4] = {v0.x, v0.y, v0.z, v0.w};
        float a1[4] = {v1.x, v1.y, v1.z, v1.w};
#pragma unroll
        for (int j = 0; j < 4; ++j) {
            int n = n4 + j;
            unsigned int u = cvt_pk_bf16(a0[j], a1[j]);
            *(unsigned int*)&xs[n*264 + (((c >> 3) ^ (n & 7)) << 3) + (c & 7)] = u;
        }
    }

    float bias_[2][4];
#pragma unroll
    for (int mt = 0; mt < 2; ++mt)
#pragma unroll
        for (int r = 0; r < 4; ++r) {
            int fg = f0 + 32*w + 16*mt + 4*g + r;
            bias_[mt][r] = (fg < 64) ? bq[fg]
                         : (fg < 128) ? bk[fg - 64] : bv[fg - 128];
        }

    // A-frags from fp32 W: af[mt][ks][j] = W[f0+32w+16mt+m][32ks+8g+j]
    const int fr0 = f0 + 32*w + m;
    const int fr1 = fr0 + 16;
    const float* wr0 = (fr0 < 64) ? Wq + (size_t)fr0*C_
                     : (fr0 < 128)? Wk + (size_t)(fr0 - 64)*C_
                                  : Wv + (size_t)(fr0 - 128)*C_;
    const float* wr1 = (fr1 < 64) ? Wq + (size_t)fr1*C_
                     : (fr1 < 128)? Wk + (size_t)(fr1 - 64)*C_
                                  : Wv + (size_t)(fr1 - 128)*C_;
    bf16x8 afr[2][8];
#pragma unroll
    for (int ks = 0; ks < 8; ++ks) {
        float4 l0 = *(const float4*)(wr0 + 32*ks + 8*g);
        float4 h0 = *(const float4*)(wr0 + 32*ks + 8*g + 4);
        float4 l1 = *(const float4*)(wr1 + 32*ks + 8*g);
        float4 h1 = *(const float4*)(wr1 + 32*ks + 8*g + 4);
        uint4 u0, u1;
        u0.x = cvt_pk_bf16(l0.x, l0.y); u0.y = cvt_pk_bf16(l0.z, l0.w);
        u0.z = cvt_pk_bf16(h0.x, h0.y); u0.w = cvt_pk_bf16(h0.z, h0.w);
        u1.x = cvt_pk_bf16(l1.x, l1.y); u1.y = cvt_pk_bf16(l1.z, l1.w);
        u1.z = cvt_pk_bf16(h1.x, h1.y); u1.w = cvt_pk_bf16(h1.z, h1.w);
        afr[0][ks] = __builtin_bit_cast(bf16x8, u0);
        afr[1][ks] = __builtin_bit_cast(bf16x8, u1);
    }

    floatx4 acc[2][4];
#pragma unroll
    for (int mt = 0; mt < 2; ++mt)
#pragma unroll
        for (int nt = 0; nt < 4; ++nt) acc[mt][nt] = (floatx4){0.f,0.f,0.f,0.f};

    __syncthreads();   // x tile staged

#pragma unroll
    for (int ks = 0; ks < 8; ++ks) {
#pragma unroll
        for (int nt = 0; nt < 4; ++nt) {
            int n = 16*nt + m;
            bf16x8 bfr = *(const bf16x8*)
                &xs[n*264 + (((4*ks + g) ^ (n & 7)) << 3)];
#pragma unroll
            for (int mt = 0; mt < 2; ++mt)
                acc[mt][nt] = __builtin_amdgcn_mfma_f32_16x16x32_bf16(
                                  afr[mt][ks], bfr, acc[mt][nt], 0, 0, 0);
        }
    }

    __syncthreads();   // xs dead -> Lt overlay

#pragma unroll
    for (int mt = 0; mt < 2; ++mt)
#pragma unroll
        for (int nt = 0; nt < 4; ++nt)
#pragma unroll
            for (int r = 0; r < 4; ++r)
                Lt[(32*w + 16*mt + 4*g + r)*72 + 16*nt + m] =
                    f2bf(acc[mt][nt][r] + bias_[mt][r]);
    __syncthreads();

    if (f0 == 0) {
#pragma unroll
        for (int k = 0; k < 4; ++k) {
            int e   = t + 256 * k;
            int fq0 = (e >> 6) * 8;
            int nl  = e & 63;
            ushort8v u;
#pragma unroll
            for (int j = 0; j < 8; ++j) u[j] = Lt[(fq0 + j)*72 + nl];
            unsigned short* dst = (fq0 < 64)
                ? (Qg + ((size_t)b*N_ + n0 + nl)*D_ + fq0)
                : (Kg + ((size_t)b*N_ + n0 + nl)*D_ + (fq0 - 64));
            *(ushort8v*)dst = u;
        }
    } else {
        const int cb = f0 - 128;
#pragma unroll
        for (int k = 0; k < 4; ++k) {
            int e  = t + 256 * k;
            int fr = e >> 3;
            int n8 = (e & 7) * 8;
            ushort8v u = *(const ushort8v*)&Lt[fr*72 + n8];
            *(ushort8v*)(Vg + ((size_t)b*C_ + cb + fr)*N_ + n0 + n8) = u;
        }
    }
}

// ---------------------------------------------------------------------------
// MFMA flash attention: R5 main loop VERBATIM (87 us, best). Combine is now
// FUSED as a last-arriver tail: after the Opart/ML epilogue, the second
// block of each (b,tile) pair (device-scope atomic on flags) normalizes
// both halves, adds gamma*... + x, and writes `out` directly. Eliminates
// the combine dispatch + launch gap; combines overlap remaining flash work.
// ---------------------------------------------------------------------------
__global__ __launch_bounds__(512, 2) void flash_kernel(
    const unsigned short* __restrict__ Qg, const unsigned short* __restrict__ Kg,
    const unsigned short* __restrict__ Vg,
    unsigned short* __restrict__ Opart, float* __restrict__ ML,
    int* __restrict__ flags, const float* __restrict__ x,
    const float* __restrict__ gamma, float* __restrict__ out)
{
    __shared__ __align__(16) unsigned short Vlds[32 * 512];    // 32 KB
    __shared__ __align__(16) unsigned short Klds[2][8 * 512];  // 16 KB
    __shared__ __align__(16) unsigned short PA[16 * 64 * 8];   // 16 KB
    __shared__ float AL[128];

    const int g8   = blockIdx.x;        // half + 2*b  (XCD pin)
    const int tile = blockIdx.y;        // 0..31 (128-query tiles)
    const int half = g8 & 1;
    const int b    = g8 >> 1;
    const int n0   = tile * 128;
    const int t    = threadIdx.x;
    const int w    = t >> 6;            // 0..7
    const int lane = t & 63;
    const int g    = lane >> 4;
    const int m    = lane & 15;
    const int wq   = w >> 2;            // PV: query-half (0..1)
    const int cq   = w & 3;             // PV: channel-quarter (0..3)

    const unsigned short* Qb = Qg + ((size_t)b*N_ + n0)*D_;
    const unsigned short* Kb = Kg + (size_t)b*N_*D_;
    const unsigned short* Vb = Vg + (size_t)b*C_*N_;

    const int cstart = half * 32;
    const int cend   = cstart + 32;

    bf16x8 qf[2];
#pragma unroll
    for (int ks = 0; ks < 2; ++ks)
        qf[ks] = *(const bf16x8*)(Qb + (size_t)(16*w + m)*D_ + 32*ks + 8*g);

    floatx4 accO[4][4];
#pragma unroll
    for (int rt = 0; rt < 4; ++rt)
#pragma unroll
        for (int ct = 0; ct < 4; ++ct)
            accO[rt][ct] = (floatx4){0.f, 0.f, 0.f, 0.f};

    float mrow = -1e30f, lrow = 0.f;

    // prologue: DMA K(cstart) into Klds[0] (one 1KB wave-op per wave)
    {
        const unsigned short* gp =
            Kb + (size_t)(cstart*64 + 16*(w >> 1) + m)*D_ + 32*(w & 1) + 8*g;
        GLOAD16(gp, &Klds[0][w * 512]);
    }
    __syncthreads();

    for (int t64 = cstart; t64 < cend; ++t64) {
        const int j0 = t64 * 64;
        const int kb = (t64 - cstart) & 1;

        // DMA V(t64): 4 wave-ops per wave (32 total)
#pragma unroll
        for (int u = 0; u < 4; ++u) {
            int sidx = 4*w + u;
            int ks   = sidx >> 4;
            int cb   = sidx & 15;
            const unsigned short* gp =
                Vb + (size_t)(16*cb + m)*N_ + j0 + 32*ks + 8*g;
            GLOAD16(gp, &Vlds[sidx * 512]);
        }
        // DMA K(t64+1) into other buffer (1 wave-op per wave)
        if (t64 + 1 < cend) {
            const unsigned short* gp =
                Kb + (size_t)((t64+1)*64 + 16*(w >> 1) + m)*D_
                   + 32*(w & 1) + 8*g;
            GLOAD16(gp, &Klds[kb ^ 1][w * 512]);
        }

        // S^T = K*Q from Klds[kb]; each wave: its 16 queries x 64 keys
        floatx4 accST[4];
#pragma unroll
        for (int jt = 0; jt < 4; ++jt) accST[jt] = (floatx4){0.f,0.f,0.f,0.f};
#pragma unroll
        for (int ks = 0; ks < 2; ++ks)
#pragma unroll
            for (int jt = 0; jt < 4; ++jt) {
                bf16x8 kfr = *(const bf16x8*)
                    &Klds[kb][(jt*2 + ks)*512 + lane*8];
                accST[jt] = __builtin_amdgcn_mfma_f32_16x16x32_bf16(
                                kfr, qf[ks], accST[jt], 0, 0, 0);
            }

        // online softmax: in-register over 16 keys/lane + 2 shfls
        float mx = -1e30f;
#pragma unroll
        for (int jt = 0; jt < 4; ++jt)
#pragma unroll
            for (int r = 0; r < 4; ++r) mx = fmaxf(mx, accST[jt][r]);
        mx = fmaxf(mx, __shfl_xor(mx, 16));
        mx = fmaxf(mx, __shfl_xor(mx, 32));
        float mnew  = fmaxf(mrow, mx);
        float alpha = __expf(mrow - mnew);
        mrow = mnew;
        float p[4][4];
        float rs = 0.f;
#pragma unroll
        for (int jt = 0; jt < 4; ++jt)
#pragma unroll
            for (int r = 0; r < 4; ++r) {
                float e = __expf(accST[jt][r] - mnew);
                p[jt][r] = e;
                rs += e;
            }
        rs += __shfl_xor(rs, 16);
        rs += __shfl_xor(rs, 32);
        lrow = lrow * alpha + rs;

        if (g == 0) AL[16*w + m] = alpha;

        // P -> LDS: HW-packed bf16 pairs, b64 stores into A-frag layout
#pragma unroll
        for (int jt = 0; jt < 4; ++jt) {
            uint2 pu;
            pu.x = cvt_pk_bf16(p[jt][0], p[jt][1]);
            pu.y = cvt_pk_bf16(p[jt][2], p[jt][3]);
            int frag = (w*2 + (jt >> 1))*64 + 16*(2*(jt & 1) + (g >> 1)) + m;
            *(uint2*)&PA[frag*8 + 4*(g & 1)] = pu;
        }

        __syncthreads();   // barrier A: drains V DMA (+K prefetch)

        // PV: O = alpha*O + P V; wave covers query-half wq x channel-qtr cq
#pragma unroll
        for (int rt = 0; rt < 4; ++rt) {
            floatx4 a4 = *(const floatx4*)&AL[64*wq + 16*rt + 4*g];
#pragma unroll
            for (int ct = 0; ct < 4; ++ct)
                accO[rt][ct] *= a4;
        }
#pragma unroll
        for (int ks = 0; ks < 2; ++ks) {
            bf16x8 pf[4];
#pragma unroll
            for (int rt = 0; rt < 4; ++rt)
                pf[rt] = *(const bf16x8*)
                    &PA[((8*wq + rt*2 + ks)*64 + lane)*8];
#pragma unroll
            for (int ct = 0; ct < 4; ++ct) {
                int sidx = ks*16 + 4*cq + ct;
                bf16x8 vfrag = *(const bf16x8*)&Vlds[sidx*512 + lane*8];
#pragma unroll
                for (int rt = 0; rt < 4; ++rt)
                    accO[rt][ct] = __builtin_amdgcn_mfma_f32_16x16x32_bf16(
                                       pf[rt], vfrag, accO[rt][ct], 0, 0, 0);
            }
        }

        __syncthreads();   // barrier B
    }

    // store unnormalized partial O (bf16) and per-query m,l
    const size_t tbase = ((size_t)(half*B_ + b)*32 + tile);
    unsigned short* Ob = Opart + tbase * (C_ * 128);
    float* ml = ML + tbase * 256;

    if (g == 0) {
        ml[16*w + m]       = mrow;
        ml[128 + 16*w + m] = lrow;
    }

#pragma unroll
    for (int rt = 0; rt < 4; ++rt)
#pragma unroll
        for (int ct = 0; ct < 4; ++ct) {
            int c  = 64*cq + 16*ct + m;
            int q0 = 64*wq + 16*rt + 4*g;
            uint2 pu;
            pu.x = cvt_pk_bf16(accO[rt][ct][0], accO[rt][ct][1]);
            pu.y = cvt_pk_bf16(accO[rt][ct][2], accO[rt][ct][3]);
            *(uint2*)(Ob + (size_t)c*128 + q0) = pu;
        }

    // ---- fused combine: second-arriving half of (b,tile) does it --------
    __threadfence();            // publish Opart/ML device-wide (cross-XCD)
    __syncthreads();            // all threads' stores fenced
    __shared__ int amLast;
    if (t == 0) amLast = (atomicAdd(&flags[b*32 + tile], 1) == 1);
    __syncthreads();
    if (!amLast) return;
    __threadfence();            // acquire side: other half's writes visible

    float* scbuf = (float*)&Klds[0][0];   // LDS dead -> reuse (1 KB)
    float* sc0_ = scbuf;
    float* sc1_ = scbuf + 128;
    if (t < 128) {
        const float* ml0 = ML + ((size_t)(0*B_ + b)*32 + tile)*256;
        const float* ml1 = ML + ((size_t)(1*B_ + b)*32 + tile)*256;
        float m0 = ml0[t], l0 = ml0[128 + t];
        float m1 = ml1[t], l1 = ml1[128 + t];
        float M  = fmaxf(m0, m1);
        float f0 = __expf(m0 - M), f1 = __expf(m1 - M);
        float L  = f0*l0 + f1*l1;
        float gm = gamma[0];
        sc0_[t] = gm * f0 / L;
        sc1_[t] = gm * f1 / L;
    }
    __syncthreads();

    const int nq = t & 31;              // query-quad (float4 column)
    const int cl = t >> 5;              // 0..15
    const float* xb = x   + (size_t)b*C_*N_;
    float*       ob = out + (size_t)b*C_*N_;
    const unsigned short* O0 = Opart + ((size_t)(0*B_ + b)*32 + tile)*(C_*128);
    const unsigned short* O1 = Opart + ((size_t)(1*B_ + b)*32 + tile)*(C_*128);

    float s0[4], s1[4];
#pragma unroll
    for (int k = 0; k < 4; ++k) { s0[k] = sc0_[4*nq + k]; s1[k] = sc1_[4*nq + k]; }

#pragma unroll 4
    for (int i = 0; i < 16; ++i) {
        int c = 16*i + cl;
        float4 x4 = *(const float4*)(xb + (size_t)c*N_ + n0 + 4*nq);
        ushort4v a4 = *(const ushort4v*)(O0 + (size_t)c*128 + 4*nq);
        ushort4v b4 = *(const ushort4v*)(O1 + (size_t)c*128 + 4*nq);
        float4 y;
        y.x = s0[0]*bf2f(a4[0]) + s1[0]*bf2f(b4[0]) + x4.x;
        y.y = s0[1]*bf2f(a4[1]) + s1[1]*bf2f(b4[1]) + x4.y;
        y.z = s0[2]*bf2f(a4[2]) + s1[2]*bf2f(b4[2]) + x4.z;
        y.w = s0[3]*bf2f(a4[3]) + s1[3]*bf2f(b4[3]) + x4.w;
        *(float4*)(ob + (size_t)c*N_ + n0 + 4*nq) = y;
    }
}

// ---------------------------------------------------------------------------
extern "C" void kernel_launch(void* const* d_in, const int* in_sizes, int n_in,
                              void* d_out, int out_size, void* d_ws, size_t ws_size,
                              hipStream_t stream) {
    const float* x     = (const float*)d_in[0];
    const float* Wq    = (const float*)d_in[1];
    const float* bq    = (const float*)d_in[2];
    const float* Wk    = (const float*)d_in[3];
    const float* bk    = (const float*)d_in[4];
    const float* Wv    = (const float*)d_in[5];
    const float* bv    = (const float*)d_in[6];
    const float* gamma = (const float*)d_in[7];
    float* out = (float*)d_out;

    // ws layout (~29.1 MB):
    unsigned short* Qg = (unsigned short*)d_ws;            // 2 MiB
    unsigned short* Kg = Qg + (size_t)B_*N_*D_;            // 2 MiB
    unsigned short* Vg = Kg + (size_t)B_*N_*D_;            // 8 MiB
    unsigned short* Op = Vg + (size_t)B_*C_*N_;            // 16.8 MiB
    float* ML = (float*)(Op + (size_t)2*B_*32*C_*128);     // 256 KiB
    int* flags = (int*)(ML + (size_t)2*B_*32*256);         // 512 B

    proj_kernel<<<dim3(64, 3, 4), 256, 0, stream>>>(x, Wq, Wk, Wv,
                                                    bq, bk, bv,
                                                    Qg, Kg, Vg, flags);
    flash_kernel<<<dim3(8, 32), 512, 0, stream>>>(Qg, Kg, Vg, Op, ML,
                                                  flags, x, gamma, out);
}

// Round 7
// 186.888 us; speedup vs baseline: 1.3916x; 1.3916x over previous
//
#include <hip/hip_runtime.h>

#define B_ 4
#define C_ 256
#define N_ 4096
#define D_ 64

typedef __bf16 bf16x8 __attribute__((ext_vector_type(8)));
typedef float floatx4 __attribute__((ext_vector_type(4)));
typedef unsigned short ushort8v __attribute__((ext_vector_type(8)));
typedef unsigned short ushort4v __attribute__((ext_vector_type(4)));
typedef unsigned short ushort2v __attribute__((ext_vector_type(2)));

static __device__ __forceinline__ unsigned short f2bf(float f) {
    unsigned int u = __builtin_bit_cast(unsigned int, f);
    u += 0x7fffu + ((u >> 16) & 1u);   // RNE
    return (unsigned short)(u >> 16);
}
static __device__ __forceinline__ float bf2f(unsigned short h) {
    unsigned int u = ((unsigned int)h) << 16;
    return __builtin_bit_cast(float, u);
}
// HW packed f32x2 -> bf16x2 (RNE), 1 VALU op
static __device__ __forceinline__ unsigned int cvt_pk_bf16(float lo, float hi) {
    unsigned int d;
    asm("v_cvt_pk_bf16_f32 %0, %1, %2" : "=v"(d) : "v"(lo), "v"(hi));
    return d;
}

// async global->LDS DMA, 16B/lane, dst = wave-uniform base + lane*16
#define GLOAD16(gp, lp)                                                      \
    __builtin_amdgcn_global_load_lds(                                        \
        (const __attribute__((address_space(1))) void*)(gp),                 \
        (__attribute__((address_space(3))) void*)(lp), 16, 0, 0)

// ---------------------------------------------------------------------------
// MFMA projection: stage x ONCE per (n-tile, b), loop all 3 f-slices
// in-block (x HBM traffic 48 -> 16 MB; staging VALU amortized 3x).
// W converted from fp32 in-block (L2-hot, 384 KB). Separate Lt buffer so
// xs stays intact across slices.
// ---------------------------------------------------------------------------
__global__ __launch_bounds__(256, 2) void proj_kernel(
    const float* __restrict__ x,
    const float* __restrict__ Wq, const float* __restrict__ Wk,
    const float* __restrict__ Wv,
    const float* __restrict__ bq, const float* __restrict__ bk,
    const float* __restrict__ bv,
    unsigned short* __restrict__ Qg, unsigned short* __restrict__ Kg,
    unsigned short* __restrict__ Vg)
{
    __shared__ __align__(16) unsigned short xs[64 * 264];   // 33792 B
    __shared__ __align__(16) unsigned short Lt[128 * 72];   // 18432 B

    const int n0 = blockIdx.x * 64;
    const int b  = blockIdx.y;
    const int t  = threadIdx.x;
    const int w  = t >> 6;
    const int lane = t & 63;
    const int g  = lane >> 4;
    const int m  = lane & 15;

    // ---- stage x tile -> LDS bf16, swizzled (once) ----
#pragma unroll
    for (int k = 0; k < 8; ++k) {
        int e  = t + 256 * k;           // 0..2047
        int cp = e >> 4;                // 0..127
        int c  = 2 * cp;
        int n4 = (e & 15) * 4;
        float4 v0 = *(const float4*)(x + ((size_t)b*C_ + c    )*N_ + n0 + n4);
        float4 v1 = *(const float4*)(x + ((size_t)b*C_ + c + 1)*N_ + n0 + n4);
        float a0[4] = {v0.x, v0.y, v0.z, v0.w};
        float a1[4] = {v1.x, v1.y, v1.z, v1.w};
#pragma unroll
        for (int j = 0; j < 4; ++j) {
            int n = n4 + j;
            unsigned int u = cvt_pk_bf16(a0[j], a1[j]);
            *(unsigned int*)&xs[n*264 + (((c >> 3) ^ (n & 7)) << 3) + (c & 7)] = u;
        }
    }
    __syncthreads();   // xs staged (stays valid for all 3 slices)

#pragma unroll
    for (int s = 0; s < 3; ++s) {
        const int f0 = 128 * s;

        float bias_[2][4];
#pragma unroll
        for (int mt = 0; mt < 2; ++mt)
#pragma unroll
            for (int r = 0; r < 4; ++r) {
                int fg = f0 + 32*w + 16*mt + 4*g + r;
                bias_[mt][r] = (fg < 64) ? bq[fg]
                             : (fg < 128) ? bk[fg - 64] : bv[fg - 128];
            }

        // A-frags from fp32 W: afr[mt][ks][j] = W[f0+32w+16mt+m][32ks+8g+j]
        const int fr0 = f0 + 32*w + m;
        const int fr1 = fr0 + 16;
        const float* wr0 = (fr0 < 64) ? Wq + (size_t)fr0*C_
                         : (fr0 < 128)? Wk + (size_t)(fr0 - 64)*C_
                                      : Wv + (size_t)(fr0 - 128)*C_;
        const float* wr1 = (fr1 < 64) ? Wq + (size_t)fr1*C_
                         : (fr1 < 128)? Wk + (size_t)(fr1 - 64)*C_
                                      : Wv + (size_t)(fr1 - 128)*C_;
        bf16x8 afr[2][8];
#pragma unroll
        for (int ks = 0; ks < 8; ++ks) {
            float4 l0 = *(const float4*)(wr0 + 32*ks + 8*g);
            float4 h0 = *(const float4*)(wr0 + 32*ks + 8*g + 4);
            float4 l1 = *(const float4*)(wr1 + 32*ks + 8*g);
            float4 h1 = *(const float4*)(wr1 + 32*ks + 8*g + 4);
            uint4 u0, u1;
            u0.x = cvt_pk_bf16(l0.x, l0.y); u0.y = cvt_pk_bf16(l0.z, l0.w);
            u0.z = cvt_pk_bf16(h0.x, h0.y); u0.w = cvt_pk_bf16(h0.z, h0.w);
            u1.x = cvt_pk_bf16(l1.x, l1.y); u1.y = cvt_pk_bf16(l1.z, l1.w);
            u1.z = cvt_pk_bf16(h1.x, h1.y); u1.w = cvt_pk_bf16(h1.z, h1.w);
            afr[0][ks] = __builtin_bit_cast(bf16x8, u0);
            afr[1][ks] = __builtin_bit_cast(bf16x8, u1);
        }

        floatx4 acc[2][4];
#pragma unroll
        for (int mt = 0; mt < 2; ++mt)
#pragma unroll
            for (int nt = 0; nt < 4; ++nt)
                acc[mt][nt] = (floatx4){0.f,0.f,0.f,0.f};

#pragma unroll
        for (int ks = 0; ks < 8; ++ks) {
#pragma unroll
            for (int nt = 0; nt < 4; ++nt) {
                int n = 16*nt + m;
                bf16x8 bfr = *(const bf16x8*)
                    &xs[n*264 + (((4*ks + g) ^ (n & 7)) << 3)];
#pragma unroll
                for (int mt = 0; mt < 2; ++mt)
                    acc[mt][nt] = __builtin_amdgcn_mfma_f32_16x16x32_bf16(
                                      afr[mt][ks], bfr, acc[mt][nt], 0, 0, 0);
            }
        }

        // epilogue via Lt (separate buffer; xs untouched)
#pragma unroll
        for (int mt = 0; mt < 2; ++mt)
#pragma unroll
            for (int nt = 0; nt < 4; ++nt)
#pragma unroll
                for (int r = 0; r < 4; ++r)
                    Lt[(32*w + 16*mt + 4*g + r)*72 + 16*nt + m] =
                        f2bf(acc[mt][nt][r] + bias_[mt][r]);
        __syncthreads();

        if (s == 0) {
#pragma unroll
            for (int k = 0; k < 4; ++k) {
                int e   = t + 256 * k;
                int fq0 = (e >> 6) * 8;
                int nl  = e & 63;
                ushort8v u;
#pragma unroll
                for (int j = 0; j < 8; ++j) u[j] = Lt[(fq0 + j)*72 + nl];
                unsigned short* dst = (fq0 < 64)
                    ? (Qg + ((size_t)b*N_ + n0 + nl)*D_ + fq0)
                    : (Kg + ((size_t)b*N_ + n0 + nl)*D_ + (fq0 - 64));
                *(ushort8v*)dst = u;
            }
        } else {
            const int cb = (s - 1) * 128;
#pragma unroll
            for (int k = 0; k < 4; ++k) {
                int e  = t + 256 * k;
                int fr = e >> 3;
                int n8 = (e & 7) * 8;
                ushort8v u = *(const ushort8v*)&Lt[fr*72 + n8];
                *(ushort8v*)(Vg + ((size_t)b*C_ + cb + fr)*N_ + n0 + n8) = u;
            }
        }
        __syncthreads();   // Lt consumed; safe for next slice's writes
    }
}

// ---------------------------------------------------------------------------
// MFMA flash attention: R5 verbatim (87 us best). 128-query tiles, 8 waves,
// split-K 2, XCD-pinned grid, K dbuf + V via global_load_lds, cvt_pk packs.
// ---------------------------------------------------------------------------
__global__ __launch_bounds__(512, 2) void flash_kernel(
    const unsigned short* __restrict__ Qg, const unsigned short* __restrict__ Kg,
    const unsigned short* __restrict__ Vg,
    unsigned short* __restrict__ Opart, float* __restrict__ ML)
{
    __shared__ __align__(16) unsigned short Vlds[32 * 512];    // 32 KB
    __shared__ __align__(16) unsigned short Klds[2][8 * 512];  // 16 KB
    __shared__ __align__(16) unsigned short PA[16 * 64 * 8];   // 16 KB
    __shared__ float AL[128];

    const int g8   = blockIdx.x;        // half + 2*b  (XCD pin)
    const int tile = blockIdx.y;        // 0..31 (128-query tiles)
    const int half = g8 & 1;
    const int b    = g8 >> 1;
    const int n0   = tile * 128;
    const int t    = threadIdx.x;
    const int w    = t >> 6;            // 0..7
    const int lane = t & 63;
    const int g    = lane >> 4;
    const int m    = lane & 15;
    const int wq   = w >> 2;            // PV: query-half (0..1)
    const int cq   = w & 3;             // PV: channel-quarter (0..3)

    const unsigned short* Qb = Qg + ((size_t)b*N_ + n0)*D_;
    const unsigned short* Kb = Kg + (size_t)b*N_*D_;
    const unsigned short* Vb = Vg + (size_t)b*C_*N_;

    const int cstart = half * 32;
    const int cend   = cstart + 32;

    bf16x8 qf[2];
#pragma unroll
    for (int ks = 0; ks < 2; ++ks)
        qf[ks] = *(const bf16x8*)(Qb + (size_t)(16*w + m)*D_ + 32*ks + 8*g);

    floatx4 accO[4][4];
#pragma unroll
    for (int rt = 0; rt < 4; ++rt)
#pragma unroll
        for (int ct = 0; ct < 4; ++ct)
            accO[rt][ct] = (floatx4){0.f, 0.f, 0.f, 0.f};

    float mrow = -1e30f, lrow = 0.f;

    // prologue: DMA K(cstart) into Klds[0] (one 1KB wave-op per wave)
    {
        const unsigned short* gp =
            Kb + (size_t)(cstart*64 + 16*(w >> 1) + m)*D_ + 32*(w & 1) + 8*g;
        GLOAD16(gp, &Klds[0][w * 512]);
    }
    __syncthreads();

    for (int t64 = cstart; t64 < cend; ++t64) {
        const int j0 = t64 * 64;
        const int kb = (t64 - cstart) & 1;

        // DMA V(t64): 4 wave-ops per wave (32 total)
#pragma unroll
        for (int u = 0; u < 4; ++u) {
            int sidx = 4*w + u;
            int ks   = sidx >> 4;
            int cb   = sidx & 15;
            const unsigned short* gp =
                Vb + (size_t)(16*cb + m)*N_ + j0 + 32*ks + 8*g;
            GLOAD16(gp, &Vlds[sidx * 512]);
        }
        // DMA K(t64+1) into other buffer (1 wave-op per wave)
        if (t64 + 1 < cend) {
            const unsigned short* gp =
                Kb + (size_t)((t64+1)*64 + 16*(w >> 1) + m)*D_
                   + 32*(w & 1) + 8*g;
            GLOAD16(gp, &Klds[kb ^ 1][w * 512]);
        }

        // S^T = K*Q from Klds[kb]; each wave: its 16 queries x 64 keys
        floatx4 accST[4];
#pragma unroll
        for (int jt = 0; jt < 4; ++jt) accST[jt] = (floatx4){0.f,0.f,0.f,0.f};
#pragma unroll
        for (int ks = 0; ks < 2; ++ks)
#pragma unroll
            for (int jt = 0; jt < 4; ++jt) {
                bf16x8 kfr = *(const bf16x8*)
                    &Klds[kb][(jt*2 + ks)*512 + lane*8];
                accST[jt] = __builtin_amdgcn_mfma_f32_16x16x32_bf16(
                                kfr, qf[ks], accST[jt], 0, 0, 0);
            }

        // online softmax: in-register over 16 keys/lane + 2 shfls
        float mx = -1e30f;
#pragma unroll
        for (int jt = 0; jt < 4; ++jt)
#pragma unroll
            for (int r = 0; r < 4; ++r) mx = fmaxf(mx, accST[jt][r]);
        mx = fmaxf(mx, __shfl_xor(mx, 16));
        mx = fmaxf(mx, __shfl_xor(mx, 32));
        float mnew  = fmaxf(mrow, mx);
        float alpha = __expf(mrow - mnew);
        mrow = mnew;
        float p[4][4];
        float rs = 0.f;
#pragma unroll
        for (int jt = 0; jt < 4; ++jt)
#pragma unroll
            for (int r = 0; r < 4; ++r) {
                float e = __expf(accST[jt][r] - mnew);
                p[jt][r] = e;
                rs += e;
            }
        rs += __shfl_xor(rs, 16);
        rs += __shfl_xor(rs, 32);
        lrow = lrow * alpha + rs;

        if (g == 0) AL[16*w + m] = alpha;

        // P -> LDS: HW-packed bf16 pairs, b64 stores into A-frag layout
#pragma unroll
        for (int jt = 0; jt < 4; ++jt) {
            uint2 pu;
            pu.x = cvt_pk_bf16(p[jt][0], p[jt][1]);
            pu.y = cvt_pk_bf16(p[jt][2], p[jt][3]);
            int frag = (w*2 + (jt >> 1))*64 + 16*(2*(jt & 1) + (g >> 1)) + m;
            *(uint2*)&PA[frag*8 + 4*(g & 1)] = pu;
        }

        __syncthreads();   // barrier A: drains V DMA (+K prefetch)

        // PV: O = alpha*O + P V; wave covers query-half wq x channel-qtr cq
#pragma unroll
        for (int rt = 0; rt < 4; ++rt) {
            floatx4 a4 = *(const floatx4*)&AL[64*wq + 16*rt + 4*g];
#pragma unroll
            for (int ct = 0; ct < 4; ++ct)
                accO[rt][ct] *= a4;
        }
#pragma unroll
        for (int ks = 0; ks < 2; ++ks) {
            bf16x8 pf[4];
#pragma unroll
            for (int rt = 0; rt < 4; ++rt)
                pf[rt] = *(const bf16x8*)
                    &PA[((8*wq + rt*2 + ks)*64 + lane)*8];
#pragma unroll
            for (int ct = 0; ct < 4; ++ct) {
                int sidx = ks*16 + 4*cq + ct;
                bf16x8 vfrag = *(const bf16x8*)&Vlds[sidx*512 + lane*8];
#pragma unroll
                for (int rt = 0; rt < 4; ++rt)
                    accO[rt][ct] = __builtin_amdgcn_mfma_f32_16x16x32_bf16(
                                       pf[rt], vfrag, accO[rt][ct], 0, 0, 0);
            }
        }

        __syncthreads();   // barrier B
    }

    // store unnormalized partial O (bf16) and per-query m,l
    const size_t tbase = ((size_t)(half*B_ + b)*32 + tile);
    unsigned short* Ob = Opart + tbase * (C_ * 128);
    float* ml = ML + tbase * 256;

    if (g == 0) {
        ml[16*w + m]       = mrow;
        ml[128 + 16*w + m] = lrow;
    }

#pragma unroll
    for (int rt = 0; rt < 4; ++rt)
#pragma unroll
        for (int ct = 0; ct < 4; ++ct) {
            int c  = 64*cq + 16*ct + m;
            int q0 = 64*wq + 16*rt + 4*g;
            uint2 pu;
            pu.x = cvt_pk_bf16(accO[rt][ct][0], accO[rt][ct][1]);
            pu.y = cvt_pk_bf16(accO[rt][ct][2], accO[rt][ct][3]);
            *(uint2*)(Ob + (size_t)c*128 + q0) = pu;
        }
}

// ---------------------------------------------------------------------------
// Combine: S=2 static, c-split across 8 blocks, 128-query tiles (R5 verbatim).
// ---------------------------------------------------------------------------
__global__ __launch_bounds__(256) void combine_kernel(
    const unsigned short* __restrict__ Opart, const float* __restrict__ ML,
    const float* __restrict__ x, const float* __restrict__ gamma,
    float* __restrict__ out)
{
    __shared__ float sc0[128], sc1[128];
    const int tile   = blockIdx.x;      // 0..31
    const int cslice = blockIdx.y;      // 0..7 (32 channels each)
    const int b      = blockIdx.z;
    const int n0     = tile * 128;
    const int t      = threadIdx.x;

    if (t < 128) {
        const float* ml0 = ML + ((size_t)(0*B_ + b)*32 + tile)*256;
        const float* ml1 = ML + ((size_t)(1*B_ + b)*32 + tile)*256;
        float m0 = ml0[t], l0 = ml0[128 + t];
        float m1 = ml1[t], l1 = ml1[128 + t];
        float M  = fmaxf(m0, m1);
        float f0 = __expf(m0 - M), f1 = __expf(m1 - M);
        float L  = f0*l0 + f1*l1;
        float gm = gamma[0];
        sc0[t] = gm * f0 / L;
        sc1[t] = gm * f1 / L;
    }
    __syncthreads();

    const int nq = t & 31;              // query-quad (float4 column)
    const int cl = t >> 5;              // 0..7
    const float* xb = x   + (size_t)b*C_*N_;
    float*       ob = out + (size_t)b*C_*N_;
    const unsigned short* O0 = Opart + ((size_t)(0*B_ + b)*32 + tile)*(C_*128);
    const unsigned short* O1 = Opart + ((size_t)(1*B_ + b)*32 + tile)*(C_*128);

    float s0[4], s1[4];
#pragma unroll
    for (int k = 0; k < 4; ++k) { s0[k] = sc0[4*nq + k]; s1[k] = sc1[4*nq + k]; }

#pragma unroll
    for (int i = 0; i < 4; ++i) {
        int c = 32*cslice + 8*i + cl;
        float4 x4 = *(const float4*)(xb + (size_t)c*N_ + n0 + 4*nq);
        ushort4v a4 = *(const ushort4v*)(O0 + (size_t)c*128 + 4*nq);
        ushort4v b4 = *(const ushort4v*)(O1 + (size_t)c*128 + 4*nq);
        float4 y;
        y.x = s0[0]*bf2f(a4[0]) + s1[0]*bf2f(b4[0]) + x4.x;
        y.y = s0[1]*bf2f(a4[1]) + s1[1]*bf2f(b4[1]) + x4.y;
        y.z = s0[2]*bf2f(a4[2]) + s1[2]*bf2f(b4[2]) + x4.z;
        y.w = s0[3]*bf2f(a4[3]) + s1[3]*bf2f(b4[3]) + x4.w;
        *(float4*)(ob + (size_t)c*N_ + n0 + 4*nq) = y;
    }
}

// ---------------------------------------------------------------------------
extern "C" void kernel_launch(void* const* d_in, const int* in_sizes, int n_in,
                              void* d_out, int out_size, void* d_ws, size_t ws_size,
                              hipStream_t stream) {
    const float* x     = (const float*)d_in[0];
    const float* Wq    = (const float*)d_in[1];
    const float* bq    = (const float*)d_in[2];
    const float* Wk    = (const float*)d_in[3];
    const float* bk    = (const float*)d_in[4];
    const float* Wv    = (const float*)d_in[5];
    const float* bv    = (const float*)d_in[6];
    const float* gamma = (const float*)d_in[7];
    float* out = (float*)d_out;

    // ws layout (~29.1 MB):
    unsigned short* Qg = (unsigned short*)d_ws;            // 2 MiB
    unsigned short* Kg = Qg + (size_t)B_*N_*D_;            // 2 MiB
    unsigned short* Vg = Kg + (size_t)B_*N_*D_;            // 8 MiB
    unsigned short* Op = Vg + (size_t)B_*C_*N_;            // 16.8 MiB
    float* ML = (float*)(Op + (size_t)2*B_*32*C_*128);     // 256 KiB

    proj_kernel<<<dim3(64, 4), 256, 0, stream>>>(x, Wq, Wk, Wv,
                                                 bq, bk, bv, Qg, Kg, Vg);
    flash_kernel<<<dim3(8, 32), 512, 0, stream>>>(Qg, Kg, Vg, Op, ML);
    combine_kernel<<<dim3(32, 8, 4), 256, 0, stream>>>(Op, ML, x, gamma, out);
}

// Round 8
// 173.150 us; speedup vs baseline: 1.5020x; 1.0793x over previous
//
#include <hip/hip_runtime.h>

#define B_ 4
#define C_ 256
#define N_ 4096
#define D_ 64

typedef __bf16 bf16x8 __attribute__((ext_vector_type(8)));
typedef float floatx4 __attribute__((ext_vector_type(4)));
typedef float floatx16 __attribute__((ext_vector_type(16)));
typedef unsigned short ushort8v __attribute__((ext_vector_type(8)));
typedef unsigned short ushort4v __attribute__((ext_vector_type(4)));
typedef unsigned short ushort2v __attribute__((ext_vector_type(2)));

static __device__ __forceinline__ unsigned short f2bf(float f) {
    unsigned int u = __builtin_bit_cast(unsigned int, f);
    u += 0x7fffu + ((u >> 16) & 1u);   // RNE
    return (unsigned short)(u >> 16);
}
static __device__ __forceinline__ float bf2f(unsigned short h) {
    unsigned int u = ((unsigned int)h) << 16;
    return __builtin_bit_cast(float, u);
}
// HW packed f32x2 -> bf16x2 (RNE), 1 VALU op; src0 -> low half
static __device__ __forceinline__ unsigned int cvt_pk_bf16(float lo, float hi) {
    unsigned int d;
    asm("v_cvt_pk_bf16_f32 %0, %1, %2" : "=v"(d) : "v"(lo), "v"(hi));
    return d;
}

// async global->LDS DMA, 16B/lane, dst = wave-uniform base + lane*16,
// src = PER-LANE global address (enables transposed staging).
#define GLOAD16(gp, lp)                                                      \
    __builtin_amdgcn_global_load_lds(                                        \
        (const __attribute__((address_space(1))) void*)(gp),                 \
        (__attribute__((address_space(3))) void*)(lp), 16, 0, 0)

// ---------------------------------------------------------------------------
// MFMA projection (R6 structure, verified): 768 blocks (64 n-tiles x 3
// f-slices x 4 b), in-block fp32->bf16 W conversion, xs/Lt LDS overlay.
// ---------------------------------------------------------------------------
__global__ __launch_bounds__(256, 3) void proj_kernel(
    const float* __restrict__ x,
    const float* __restrict__ Wq, const float* __restrict__ Wk,
    const float* __restrict__ Wv,
    const float* __restrict__ bq, const float* __restrict__ bk,
    const float* __restrict__ bv,
    unsigned short* __restrict__ Qg, unsigned short* __restrict__ Kg,
    unsigned short* __restrict__ Vg)
{
    __shared__ __align__(16) unsigned short smem[64 * 264];  // 33792 B
    unsigned short* xs = smem;          // x tile, swizzled [n][264]
    unsigned short* Lt = smem;          // epilogue tile [128][72] (union)

    const int n0 = blockIdx.x * 64;
    const int f0 = blockIdx.y * 128;
    const int b  = blockIdx.z;
    const int t  = threadIdx.x;
    const int w  = t >> 6;
    const int lane = t & 63;
    const int g  = lane >> 4;
    const int m  = lane & 15;

#pragma unroll
    for (int k = 0; k < 8; ++k) {
        int e  = t + 256 * k;           // 0..2047
        int cp = e >> 4;                // 0..127
        int c  = 2 * cp;
        int n4 = (e & 15) * 4;
        float4 v0 = *(const float4*)(x + ((size_t)b*C_ + c    )*N_ + n0 + n4);
        float4 v1 = *(const float4*)(x + ((size_t)b*C_ + c + 1)*N_ + n0 + n4);
        float a0[4] = {v0.x, v0.y, v0.z, v0.w};
        float a1[4] = {v1.x, v1.y, v1.z, v1.w};
#pragma unroll
        for (int j = 0; j < 4; ++j) {
            int n = n4 + j;
            unsigned int u = cvt_pk_bf16(a0[j], a1[j]);
            *(unsigned int*)&xs[n*264 + (((c >> 3) ^ (n & 7)) << 3) + (c & 7)] = u;
        }
    }

    float bias_[2][4];
#pragma unroll
    for (int mt = 0; mt < 2; ++mt)
#pragma unroll
        for (int r = 0; r < 4; ++r) {
            int fg = f0 + 32*w + 16*mt + 4*g + r;
            bias_[mt][r] = (fg < 64) ? bq[fg]
                         : (fg < 128) ? bk[fg - 64] : bv[fg - 128];
        }

    // A-frags from fp32 W
    const int fr0 = f0 + 32*w + m;
    const int fr1 = fr0 + 16;
    const float* wr0 = (fr0 < 64) ? Wq + (size_t)fr0*C_
                     : (fr0 < 128)? Wk + (size_t)(fr0 - 64)*C_
                                  : Wv + (size_t)(fr0 - 128)*C_;
    const float* wr1 = (fr1 < 64) ? Wq + (size_t)fr1*C_
                     : (fr1 < 128)? Wk + (size_t)(fr1 - 64)*C_
                                  : Wv + (size_t)(fr1 - 128)*C_;
    bf16x8 afr[2][8];
#pragma unroll
    for (int ks = 0; ks < 8; ++ks) {
        float4 l0 = *(const float4*)(wr0 + 32*ks + 8*g);
        float4 h0 = *(const float4*)(wr0 + 32*ks + 8*g + 4);
        float4 l1 = *(const float4*)(wr1 + 32*ks + 8*g);
        float4 h1 = *(const float4*)(wr1 + 32*ks + 8*g + 4);
        uint4 u0, u1;
        u0.x = cvt_pk_bf16(l0.x, l0.y); u0.y = cvt_pk_bf16(l0.z, l0.w);
        u0.z = cvt_pk_bf16(h0.x, h0.y); u0.w = cvt_pk_bf16(h0.z, h0.w);
        u1.x = cvt_pk_bf16(l1.x, l1.y); u1.y = cvt_pk_bf16(l1.z, l1.w);
        u1.z = cvt_pk_bf16(h1.x, h1.y); u1.w = cvt_pk_bf16(h1.z, h1.w);
        afr[0][ks] = __builtin_bit_cast(bf16x8, u0);
        afr[1][ks] = __builtin_bit_cast(bf16x8, u1);
    }

    floatx4 acc[2][4];
#pragma unroll
    for (int mt = 0; mt < 2; ++mt)
#pragma unroll
        for (int nt = 0; nt < 4; ++nt) acc[mt][nt] = (floatx4){0.f,0.f,0.f,0.f};

    __syncthreads();   // x tile staged

#pragma unroll
    for (int ks = 0; ks < 8; ++ks) {
#pragma unroll
        for (int nt = 0; nt < 4; ++nt) {
            int n = 16*nt + m;
            bf16x8 bfr = *(const bf16x8*)
                &xs[n*264 + (((4*ks + g) ^ (n & 7)) << 3)];
#pragma unroll
            for (int mt = 0; mt < 2; ++mt)
                acc[mt][nt] = __builtin_amdgcn_mfma_f32_16x16x32_bf16(
                                  afr[mt][ks], bfr, acc[mt][nt], 0, 0, 0);
        }
    }

    __syncthreads();   // xs dead -> Lt overlay

#pragma unroll
    for (int mt = 0; mt < 2; ++mt)
#pragma unroll
        for (int nt = 0; nt < 4; ++nt)
#pragma unroll
            for (int r = 0; r < 4; ++r)
                Lt[(32*w + 16*mt + 4*g + r)*72 + 16*nt + m] =
                    f2bf(acc[mt][nt][r] + bias_[mt][r]);
    __syncthreads();

    if (f0 == 0) {
#pragma unroll
        for (int k = 0; k < 4; ++k) {
            int e   = t + 256 * k;
            int fq0 = (e >> 6) * 8;
            int nl  = e & 63;
            ushort8v u;
#pragma unroll
            for (int j = 0; j < 8; ++j) u[j] = Lt[(fq0 + j)*72 + nl];
            unsigned short* dst = (fq0 < 64)
                ? (Qg + ((size_t)b*N_ + n0 + nl)*D_ + fq0)
                : (Kg + ((size_t)b*N_ + n0 + nl)*D_ + (fq0 - 64));
            *(ushort8v*)dst = u;
        }
    } else {
        const int cb = f0 - 128;
#pragma unroll
        for (int k = 0; k < 4; ++k) {
            int e  = t + 256 * k;
            int fr = e >> 3;
            int n8 = (e & 7) * 8;
            ushort8v u = *(const ushort8v*)&Lt[fr*72 + n8];
            *(ushort8v*)(Vg + ((size_t)b*C_ + cb + fr)*N_ + n0 + n8) = u;
        }
    }
}

// ---------------------------------------------------------------------------
// Flash attention, 32x32x16 restructure: 256-query blocks, 8 waves x 32q,
// split-K 4 (grid (16,16) = 256 blocks = 1/CU). Each wave owns 32 queries x
// ALL 256 channels: ST C (col=lane&31=query) matches PV A (row=lane&31=query)
// so P stays IN REGISTER — cvt_pk + v_permlane32_swap builds PV A-frags
// (no PA LDS, no P-handoff barrier). K/V staged via gload_lds with per-lane
// TRANSPOSED global src so frag reads are lane-linear. V+K double-buffered:
// ONE barrier per 64-key tile, full-iteration DMA cover.
// ---------------------------------------------------------------------------
__global__ __launch_bounds__(512, 2) void flash_kernel(
    const unsigned short* __restrict__ Qg, const unsigned short* __restrict__ Kg,
    const unsigned short* __restrict__ Vg,
    unsigned short* __restrict__ Opart, float* __restrict__ ML)
{
    __shared__ __align__(16) unsigned short Vlds[2][32 * 512];  // 64 KB
    __shared__ __align__(16) unsigned short Klds[2][8 * 512];   // 16 KB
    __shared__ float AL[8][32];                                 //  1 KB

    const int gx   = blockIdx.x;        // quarter + 4*b (XCD pin: gx%8)
    const int tile = blockIdx.y;        // 0..15 (256-query tiles)
    const int quarter = gx & 3;
    const int b    = gx >> 2;
    const int n0   = tile * 256;
    const int t    = threadIdx.x;
    const int w    = t >> 6;            // 0..7
    const int lane = t & 63;
    const int q32  = lane & 31;         // query within wave / col index
    const int h    = lane >> 5;         // lane half

    const unsigned short* Qb = Qg + ((size_t)b*N_ + n0)*D_;
    const unsigned short* Kb = Kg + (size_t)b*N_*D_;
    const unsigned short* Vb = Vg + (size_t)b*C_*N_;

    const int cstart = quarter * 16;
    const int cend   = cstart + 16;

    // Q B-frags (stationary): col=q32, k=8h+j per 16-chunk ks
    bf16x8 qf[4];
#pragma unroll
    for (int ks = 0; ks < 4; ++ks)
        qf[ks] = *(const bf16x8*)(Qb + (size_t)(32*w + q32)*D_ + 16*ks + 8*h);

    floatx16 accO[8];
#pragma unroll
    for (int ct = 0; ct < 8; ++ct)
#pragma unroll
        for (int r = 0; r < 16; ++r) accO[ct][r] = 0.f;

    float mrow = -1e30f, lrow = 0.f;

// K tile (8KB): op per wave; A-frag-native: slot (kt*4+ks)=w holds
// K[32kt+q32][16ks+8h+j], dst linear lane*16B.
#define STAGE_K(T64, BUF) do {                                               \
    const unsigned short* gp = Kb                                            \
        + (size_t)((T64)*64 + 32*(w >> 2) + q32)*D_ + 16*(w & 3) + 8*h;      \
    GLOAD16(gp, &Klds[BUF][w * 512]); } while (0)

// V tile (32KB): wave w stages its channel-block ct=w, 4 kc-chunks;
// slot (ct*4+kc) holds V[j0+16kc+8h+j][32ct+q32] B-frag-native.
#define STAGE_V(T64, BUF) do {                                               \
    _Pragma("unroll")                                                        \
    for (int u_ = 0; u_ < 4; ++u_) {                                         \
        const unsigned short* gp = Vb                                        \
            + (size_t)(32*w + q32)*N_ + (T64)*64 + 16*u_ + 8*h;              \
        GLOAD16(gp, &Vlds[BUF][(w*4 + u_) * 512]);                           \
    } } while (0)

    // prologue
    STAGE_K(cstart, 0);
    STAGE_V(cstart, 0);
    __syncthreads();

    for (int t64 = cstart; t64 < cend; ++t64) {
        const int cur = (t64 - cstart) & 1;

        // prefetch next tile into other buffers (drained at end-of-iter barrier)
        if (t64 + 1 < cend) {
            STAGE_K(t64 + 1, cur ^ 1);
            STAGE_V(t64 + 1, cur ^ 1);
        }

        // ST = K*Q (32x32x16): accS[kt] over ks; C: col=q32, row-key per reg
        floatx16 accS[2];
#pragma unroll
        for (int kt = 0; kt < 2; ++kt)
#pragma unroll
            for (int r = 0; r < 16; ++r) accS[kt][r] = 0.f;
#pragma unroll
        for (int kt = 0; kt < 2; ++kt)
#pragma unroll
            for (int ks = 0; ks < 4; ++ks) {
                bf16x8 kfr = *(const bf16x8*)
                    &Klds[cur][(kt*4 + ks)*512 + lane*8];
                accS[kt] = __builtin_amdgcn_mfma_f32_32x32x16_bf16(
                               kfr, qf[ks], accS[kt], 0, 0, 0);
            }

        // online softmax: 32 scores/lane (half the 64 keys; partner = lane^32)
        float mx = -1e30f;
#pragma unroll
        for (int kt = 0; kt < 2; ++kt)
#pragma unroll
            for (int r = 0; r < 16; ++r) mx = fmaxf(mx, accS[kt][r]);
        mx = fmaxf(mx, __shfl_xor(mx, 32));
        float mnew  = fmaxf(mrow, mx);
        float alpha = __expf(mrow - mnew);
        mrow = mnew;
        float p[2][16];
        float rs = 0.f;
#pragma unroll
        for (int kt = 0; kt < 2; ++kt)
#pragma unroll
            for (int r = 0; r < 16; ++r) {
                float e = __expf(accS[kt][r] - mnew);
                p[kt][r] = e;
                rs += e;
            }
        rs += __shfl_xor(rs, 32);
        lrow = lrow * alpha + rs;
        if (h == 0) AL[w][q32] = alpha;

        // P -> PV A-frags IN REGISTER: per 16-key chunk, 4 cvt_pk + 2 permlane
        // swaps. Key(reg r) = (r&3)+8*(r>>2)+4h; A-frag k = 8h+j.
        bf16x8 pa[4];
#pragma unroll
        for (int kt = 0; kt < 2; ++kt)
#pragma unroll
            for (int cp = 0; cp < 2; ++cp) {
                unsigned int Y0 = cvt_pk_bf16(p[kt][8*cp + 0], p[kt][8*cp + 1]);
                unsigned int Y1 = cvt_pk_bf16(p[kt][8*cp + 2], p[kt][8*cp + 3]);
                unsigned int X0 = cvt_pk_bf16(p[kt][8*cp + 4], p[kt][8*cp + 5]);
                unsigned int X1 = cvt_pk_bf16(p[kt][8*cp + 6], p[kt][8*cp + 7]);
                asm volatile("v_permlane32_swap_b32 %0, %1"
                             : "+v"(Y0), "+v"(X0));
                asm volatile("v_permlane32_swap_b32 %0, %1"
                             : "+v"(Y1), "+v"(X1));
                uint4 fu; fu.x = Y0; fu.y = Y1; fu.z = X0; fu.w = X1;
                pa[kt*2 + cp] = __builtin_bit_cast(bf16x8, fu);
            }

        // alpha rescale: accO reg r belongs to query (r&3)+8*(r>>2)+4h
        float4 av[4];
#pragma unroll
        for (int gp = 0; gp < 4; ++gp)
            av[gp] = *(const float4*)&AL[w][8*gp + 4*h];
#pragma unroll
        for (int ct = 0; ct < 8; ++ct)
#pragma unroll
            for (int gp = 0; gp < 4; ++gp)
#pragma unroll
                for (int i = 0; i < 4; ++i)
                    accO[ct][4*gp + i] *= av[gp][i];

        // PV: O += P V (32x32x16), wave-private — no cross-wave dependency
        __builtin_amdgcn_s_setprio(1);
#pragma unroll
        for (int ct = 0; ct < 8; ++ct)
#pragma unroll
            for (int kc = 0; kc < 4; ++kc) {
                bf16x8 vf = *(const bf16x8*)
                    &Vlds[cur][(ct*4 + kc)*512 + lane*8];
                accO[ct] = __builtin_amdgcn_mfma_f32_32x32x16_bf16(
                               pa[kc], vf, accO[ct], 0, 0, 0);
            }
        __builtin_amdgcn_s_setprio(0);

        // ONE barrier/iter: drains next-tile DMA (full-iter cover) and
        // fences Vlds/Klds[cur] reuse.
        __syncthreads();
    }

    // epilogue: unnormalized partial O (bf16) + per-query m,l
    const size_t tbase = ((size_t)(quarter*B_ + b)*16 + tile);
    unsigned short* Ob = Opart + tbase * (C_ * 256);
    float* ml = ML + tbase * 512;

    if (h == 0) {
        ml[32*w + q32]       = mrow;
        ml[256 + 32*w + q32] = lrow;
    }

#pragma unroll
    for (int ct = 0; ct < 8; ++ct) {
        int c = 32*ct + q32;
#pragma unroll
        for (int gp = 0; gp < 4; ++gp) {
            uint2 pu;
            pu.x = cvt_pk_bf16(accO[ct][4*gp + 0], accO[ct][4*gp + 1]);
            pu.y = cvt_pk_bf16(accO[ct][4*gp + 2], accO[ct][4*gp + 3]);
            *(uint2*)(Ob + (size_t)c*256 + 32*w + 8*gp + 4*h) = pu;
        }
    }
#undef STAGE_K
#undef STAGE_V
}

// ---------------------------------------------------------------------------
// Combine: S=4 static, 256-query tiles, 32 channels per block.
// ---------------------------------------------------------------------------
__global__ __launch_bounds__(256) void combine_kernel(
    const unsigned short* __restrict__ Opart, const float* __restrict__ ML,
    const float* __restrict__ x, const float* __restrict__ gamma,
    float* __restrict__ out)
{
    __shared__ float sc[4][256];
    const int tile   = blockIdx.x;      // 0..15
    const int cslice = blockIdx.y;      // 0..7
    const int b      = blockIdx.z;
    const int n0     = tile * 256;
    const int t      = threadIdx.x;     // 0..255 (= query for phase 1)

    {
        float mm[4], ll[4];
        float M = -1e30f;
#pragma unroll
        for (int s = 0; s < 4; ++s) {
            const float* mls = ML + ((size_t)(s*B_ + b)*16 + tile)*512;
            mm[s] = mls[t];
            ll[s] = mls[256 + t];
            M = fmaxf(M, mm[s]);
        }
        float fs[4];
        float L = 0.f;
#pragma unroll
        for (int s = 0; s < 4; ++s) { fs[s] = __expf(mm[s] - M); L += fs[s]*ll[s]; }
        float gm = gamma[0];
#pragma unroll
        for (int s = 0; s < 4; ++s) sc[s][t] = gm * fs[s] / L;
    }
    __syncthreads();

    const int nq = t & 63;              // query-quad (float4 column)
    const int cl = t >> 6;              // 0..3
    const float* xb = x   + (size_t)b*C_*N_;
    float*       ob = out + (size_t)b*C_*N_;
    const unsigned short* Os[4];
#pragma unroll
    for (int s = 0; s < 4; ++s)
        Os[s] = Opart + ((size_t)(s*B_ + b)*16 + tile)*(C_*256);

    float sv[4][4];
#pragma unroll
    for (int s = 0; s < 4; ++s)
#pragma unroll
        for (int k = 0; k < 4; ++k) sv[s][k] = sc[s][4*nq + k];

#pragma unroll
    for (int i = 0; i < 8; ++i) {
        int c = 32*cslice + 4*i + cl;
        float4 x4 = *(const float4*)(xb + (size_t)c*N_ + n0 + 4*nq);
        float4 y = x4;
#pragma unroll
        for (int s = 0; s < 4; ++s) {
            ushort4v a4 = *(const ushort4v*)(Os[s] + (size_t)c*256 + 4*nq);
            y.x += sv[s][0]*bf2f(a4[0]);
            y.y += sv[s][1]*bf2f(a4[1]);
            y.z += sv[s][2]*bf2f(a4[2]);
            y.w += sv[s][3]*bf2f(a4[3]);
        }
        *(float4*)(ob + (size_t)c*N_ + n0 + 4*nq) = y;
    }
}

// ---------------------------------------------------------------------------
extern "C" void kernel_launch(void* const* d_in, const int* in_sizes, int n_in,
                              void* d_out, int out_size, void* d_ws, size_t ws_size,
                              hipStream_t stream) {
    const float* x     = (const float*)d_in[0];
    const float* Wq    = (const float*)d_in[1];
    const float* bq    = (const float*)d_in[2];
    const float* Wk    = (const float*)d_in[3];
    const float* bk    = (const float*)d_in[4];
    const float* Wv    = (const float*)d_in[5];
    const float* bv    = (const float*)d_in[6];
    const float* gamma = (const float*)d_in[7];
    float* out = (float*)d_out;

    // ws layout (~46.1 MB):
    unsigned short* Qg = (unsigned short*)d_ws;            // 2 MiB
    unsigned short* Kg = Qg + (size_t)B_*N_*D_;            // 2 MiB
    unsigned short* Vg = Kg + (size_t)B_*N_*D_;            // 8 MiB
    unsigned short* Op = Vg + (size_t)B_*C_*N_;            // 33.6 MiB (S=4)
    float* ML = (float*)(Op + (size_t)4*B_*16*C_*256);     // 512 KiB

    proj_kernel<<<dim3(64, 3, 4), 256, 0, stream>>>(x, Wq, Wk, Wv,
                                                    bq, bk, bv, Qg, Kg, Vg);
    flash_kernel<<<dim3(16, 16), 512, 0, stream>>>(Qg, Kg, Vg, Op, ML);
    combine_kernel<<<dim3(16, 8, 4), 256, 0, stream>>>(Op, ML, x, gamma, out);
}

// Round 9
// 169.697 us; speedup vs baseline: 1.5326x; 1.0203x over previous
//
#include <hip/hip_runtime.h>

#define B_ 4
#define C_ 256
#define N_ 4096
#define D_ 64

typedef __bf16 bf16x8 __attribute__((ext_vector_type(8)));
typedef float floatx4 __attribute__((ext_vector_type(4)));
typedef float floatx16 __attribute__((ext_vector_type(16)));
typedef unsigned short ushort8v __attribute__((ext_vector_type(8)));
typedef unsigned short ushort4v __attribute__((ext_vector_type(4)));
typedef unsigned short ushort2v __attribute__((ext_vector_type(2)));

static __device__ __forceinline__ unsigned short f2bf(float f) {
    unsigned int u = __builtin_bit_cast(unsigned int, f);
    u += 0x7fffu + ((u >> 16) & 1u);   // RNE
    return (unsigned short)(u >> 16);
}
static __device__ __forceinline__ float bf2f(unsigned short h) {
    unsigned int u = ((unsigned int)h) << 16;
    return __builtin_bit_cast(float, u);
}
// HW packed f32x2 -> bf16x2 (RNE), 1 VALU op; src0 -> low half
static __device__ __forceinline__ unsigned int cvt_pk_bf16(float lo, float hi) {
    unsigned int d;
    asm("v_cvt_pk_bf16_f32 %0, %1, %2" : "=v"(d) : "v"(lo), "v"(hi));
    return d;
}

// async global->LDS DMA, 16B/lane, dst = wave-uniform base + lane*16,
// src = PER-LANE global address (enables transposed staging).
#define GLOAD16(gp, lp)                                                      \
    __builtin_amdgcn_global_load_lds(                                        \
        (const __attribute__((address_space(1))) void*)(gp),                 \
        (__attribute__((address_space(3))) void*)(lp), 16, 0, 0)

// ---------------------------------------------------------------------------
// MFMA projection (R6/R8 structure, verified): 768 blocks (64 n-tiles x 3
// f-slices x 4 b), in-block fp32->bf16 W conversion, xs/Lt LDS overlay.
// ---------------------------------------------------------------------------
__global__ __launch_bounds__(256, 3) void proj_kernel(
    const float* __restrict__ x,
    const float* __restrict__ Wq, const float* __restrict__ Wk,
    const float* __restrict__ Wv,
    const float* __restrict__ bq, const float* __restrict__ bk,
    const float* __restrict__ bv,
    unsigned short* __restrict__ Qg, unsigned short* __restrict__ Kg,
    unsigned short* __restrict__ Vg)
{
    __shared__ __align__(16) unsigned short smem[64 * 264];  // 33792 B
    unsigned short* xs = smem;          // x tile, swizzled [n][264]
    unsigned short* Lt = smem;          // epilogue tile [128][72] (union)

    const int n0 = blockIdx.x * 64;
    const int f0 = blockIdx.y * 128;
    const int b  = blockIdx.z;
    const int t  = threadIdx.x;
    const int w  = t >> 6;
    const int lane = t & 63;
    const int g  = lane >> 4;
    const int m  = lane & 15;

#pragma unroll
    for (int k = 0; k < 8; ++k) {
        int e  = t + 256 * k;           // 0..2047
        int cp = e >> 4;                // 0..127
        int c  = 2 * cp;
        int n4 = (e & 15) * 4;
        float4 v0 = *(const float4*)(x + ((size_t)b*C_ + c    )*N_ + n0 + n4);
        float4 v1 = *(const float4*)(x + ((size_t)b*C_ + c + 1)*N_ + n0 + n4);
        float a0[4] = {v0.x, v0.y, v0.z, v0.w};
        float a1[4] = {v1.x, v1.y, v1.z, v1.w};
#pragma unroll
        for (int j = 0; j < 4; ++j) {
            int n = n4 + j;
            unsigned int u = cvt_pk_bf16(a0[j], a1[j]);
            *(unsigned int*)&xs[n*264 + (((c >> 3) ^ (n & 7)) << 3) + (c & 7)] = u;
        }
    }

    float bias_[2][4];
#pragma unroll
    for (int mt = 0; mt < 2; ++mt)
#pragma unroll
        for (int r = 0; r < 4; ++r) {
            int fg = f0 + 32*w + 16*mt + 4*g + r;
            bias_[mt][r] = (fg < 64) ? bq[fg]
                         : (fg < 128) ? bk[fg - 64] : bv[fg - 128];
        }

    // A-frags from fp32 W
    const int fr0 = f0 + 32*w + m;
    const int fr1 = fr0 + 16;
    const float* wr0 = (fr0 < 64) ? Wq + (size_t)fr0*C_
                     : (fr0 < 128)? Wk + (size_t)(fr0 - 64)*C_
                                  : Wv + (size_t)(fr0 - 128)*C_;
    const float* wr1 = (fr1 < 64) ? Wq + (size_t)fr1*C_
                     : (fr1 < 128)? Wk + (size_t)(fr1 - 64)*C_
                                  : Wv + (size_t)(fr1 - 128)*C_;
    bf16x8 afr[2][8];
#pragma unroll
    for (int ks = 0; ks < 8; ++ks) {
        float4 l0 = *(const float4*)(wr0 + 32*ks + 8*g);
        float4 h0 = *(const float4*)(wr0 + 32*ks + 8*g + 4);
        float4 l1 = *(const float4*)(wr1 + 32*ks + 8*g);
        float4 h1 = *(const float4*)(wr1 + 32*ks + 8*g + 4);
        uint4 u0, u1;
        u0.x = cvt_pk_bf16(l0.x, l0.y); u0.y = cvt_pk_bf16(l0.z, l0.w);
        u0.z = cvt_pk_bf16(h0.x, h0.y); u0.w = cvt_pk_bf16(h0.z, h0.w);
        u1.x = cvt_pk_bf16(l1.x, l1.y); u1.y = cvt_pk_bf16(l1.z, l1.w);
        u1.z = cvt_pk_bf16(h1.x, h1.y); u1.w = cvt_pk_bf16(h1.z, h1.w);
        afr[0][ks] = __builtin_bit_cast(bf16x8, u0);
        afr[1][ks] = __builtin_bit_cast(bf16x8, u1);
    }

    floatx4 acc[2][4];
#pragma unroll
    for (int mt = 0; mt < 2; ++mt)
#pragma unroll
        for (int nt = 0; nt < 4; ++nt) acc[mt][nt] = (floatx4){0.f,0.f,0.f,0.f};

    __syncthreads();   // x tile staged

#pragma unroll
    for (int ks = 0; ks < 8; ++ks) {
#pragma unroll
        for (int nt = 0; nt < 4; ++nt) {
            int n = 16*nt + m;
            bf16x8 bfr = *(const bf16x8*)
                &xs[n*264 + (((4*ks + g) ^ (n & 7)) << 3)];
#pragma unroll
            for (int mt = 0; mt < 2; ++mt)
                acc[mt][nt] = __builtin_amdgcn_mfma_f32_16x16x32_bf16(
                                  afr[mt][ks], bfr, acc[mt][nt], 0, 0, 0);
        }
    }

    __syncthreads();   // xs dead -> Lt overlay

#pragma unroll
    for (int mt = 0; mt < 2; ++mt)
#pragma unroll
        for (int nt = 0; nt < 4; ++nt)
#pragma unroll
            for (int r = 0; r < 4; ++r)
                Lt[(32*w + 16*mt + 4*g + r)*72 + 16*nt + m] =
                    f2bf(acc[mt][nt][r] + bias_[mt][r]);
    __syncthreads();

    if (f0 == 0) {
#pragma unroll
        for (int k = 0; k < 4; ++k) {
            int e   = t + 256 * k;
            int fq0 = (e >> 6) * 8;
            int nl  = e & 63;
            ushort8v u;
#pragma unroll
            for (int j = 0; j < 8; ++j) u[j] = Lt[(fq0 + j)*72 + nl];
            unsigned short* dst = (fq0 < 64)
                ? (Qg + ((size_t)b*N_ + n0 + nl)*D_ + fq0)
                : (Kg + ((size_t)b*N_ + n0 + nl)*D_ + (fq0 - 64));
            *(ushort8v*)dst = u;
        }
    } else {
        const int cb = f0 - 128;
#pragma unroll
        for (int k = 0; k < 4; ++k) {
            int e  = t + 256 * k;
            int fr = e >> 3;
            int n8 = (e & 7) * 8;
            ushort8v u = *(const ushort8v*)&Lt[fr*72 + n8];
            *(ushort8v*)(Vg + ((size_t)b*C_ + cb + fr)*N_ + n0 + n8) = u;
        }
    }
}

// ---------------------------------------------------------------------------
// Flash attention 32x32x16 (R8 base, PASSED) + one-tile-lag PV pipeline +
// defer-max. Iteration t: [prefetch V(t+1)/K(t+1)] -> ST(t) -> [rescale? +
// PV(t-1) from pa_prev regs & Vlds[(t-1)%3]] -> softmax(t) -> pa_prev(t).
// PV(t-1) is independent of softmax(t) -> MFMA overlaps VALU. V triple-
// buffered (DMA writes (t+1)%3, PV reads (t-1)%3 — disjoint; barrier at
// iter end separates buffer reuse, one barrier/iter). Defer-max: if all
// lanes' tile-max is within 8 of the running max, keep the stale max
// (alpha=1) and SKIP the 128-elem accO rescale + AL write (bounded by e^8).
// ---------------------------------------------------------------------------
__global__ __launch_bounds__(512, 2) void flash_kernel(
    const unsigned short* __restrict__ Qg, const unsigned short* __restrict__ Kg,
    const unsigned short* __restrict__ Vg,
    unsigned short* __restrict__ Opart, float* __restrict__ ML)
{
    __shared__ __align__(16) unsigned short Vlds[3][32 * 512];  // 96 KB
    __shared__ __align__(16) unsigned short Klds[2][8 * 512];   // 16 KB
    __shared__ float AL[8][32];                                 //  1 KB

    const int gx   = blockIdx.x;        // quarter + 4*b (XCD pin: gx%8)
    const int tile = blockIdx.y;        // 0..15 (256-query tiles)
    const int quarter = gx & 3;
    const int b    = gx >> 2;
    const int n0   = tile * 256;
    const int t    = threadIdx.x;
    const int w    = t >> 6;            // 0..7
    const int lane = t & 63;
    const int q32  = lane & 31;         // query within wave / col index
    const int h    = lane >> 5;         // lane half

    const unsigned short* Qb = Qg + ((size_t)b*N_ + n0)*D_;
    const unsigned short* Kb = Kg + (size_t)b*N_*D_;
    const unsigned short* Vb = Vg + (size_t)b*C_*N_;

    const int cstart = quarter * 16;
    const int cend   = cstart + 16;

    // Q B-frags (stationary): col=q32, k=8h+j per 16-chunk ks
    bf16x8 qf[4];
#pragma unroll
    for (int ks = 0; ks < 4; ++ks)
        qf[ks] = *(const bf16x8*)(Qb + (size_t)(32*w + q32)*D_ + 16*ks + 8*h);

    floatx16 accO[8];
#pragma unroll
    for (int ct = 0; ct < 8; ++ct)
#pragma unroll
        for (int r = 0; r < 16; ++r) accO[ct][r] = 0.f;

    float mrow = -1e30f, lrow = 0.f;
    bf16x8 pa_prev[4];
    bool skip_prev = true;              // no pending PV before first iter

// K tile (8KB): one op per wave; A-frag-native: slot (kt*4+ks)=w holds
// K[32kt+q32][16ks+8h+j], dst linear lane*16B.
#define STAGE_K(T64, BUF) do {                                               \
    const unsigned short* gp = Kb                                            \
        + (size_t)((T64)*64 + 32*(w >> 2) + q32)*D_ + 16*(w & 3) + 8*h;      \
    GLOAD16(gp, &Klds[BUF][w * 512]); } while (0)

// V tile (32KB): wave w stages its channel-block ct=w, 4 kc-chunks;
// slot (ct*4+kc) holds V[j0+16kc+8h+j][32ct+q32] B-frag-native.
#define STAGE_V(T64, BUF) do {                                               \
    _Pragma("unroll")                                                        \
    for (int u_ = 0; u_ < 4; ++u_) {                                         \
        const unsigned short* gp = Vb                                        \
            + (size_t)(32*w + q32)*N_ + (T64)*64 + 16*u_ + 8*h;              \
        GLOAD16(gp, &Vlds[BUF][(w*4 + u_) * 512]);                           \
    } } while (0)

// one pipelined iteration
#define FITER(T64, HASPV, HASPRE) do {                                       \
    if (HASPRE) { STAGE_K((T64)+1, kcur ^ 1); STAGE_V((T64)+1, vnxt); }      \
    /* ST(T64) = K*Q */                                                      \
    floatx16 accS[2];                                                        \
    _Pragma("unroll")                                                        \
    for (int kt = 0; kt < 2; ++kt)                                           \
        _Pragma("unroll")                                                    \
        for (int r = 0; r < 16; ++r) accS[kt][r] = 0.f;                      \
    _Pragma("unroll")                                                        \
    for (int kt = 0; kt < 2; ++kt)                                           \
        _Pragma("unroll")                                                    \
        for (int ks = 0; ks < 4; ++ks) {                                     \
            bf16x8 kfr = *(const bf16x8*)                                    \
                &Klds[kcur][(kt*4 + ks)*512 + lane*8];                       \
            accS[kt] = __builtin_amdgcn_mfma_f32_32x32x16_bf16(              \
                           kfr, qf[ks], accS[kt], 0, 0, 0);                  \
        }                                                                    \
    /* PV(T64-1): independent of softmax below -> overlaps it */             \
    if (HASPV) {                                                             \
        if (!skip_prev) {                                                    \
            float4 av_[4];                                                   \
            _Pragma("unroll")                                                \
            for (int gp_ = 0; gp_ < 4; ++gp_)                                \
                av_[gp_] = *(const float4*)&AL[w][8*gp_ + 4*h];              \
            _Pragma("unroll")                                                \
            for (int ct = 0; ct < 8; ++ct)                                   \
                _Pragma("unroll")                                            \
                for (int gp_ = 0; gp_ < 4; ++gp_)                            \
                    _Pragma("unroll")                                        \
                    for (int i_ = 0; i_ < 4; ++i_)                           \
                        accO[ct][4*gp_ + i_] *= av_[gp_][i_];                \
        }                                                                    \
        __builtin_amdgcn_s_setprio(1);                                       \
        _Pragma("unroll")                                                    \
        for (int ct = 0; ct < 8; ++ct)                                       \
            _Pragma("unroll")                                                \
            for (int kc = 0; kc < 4; ++kc) {                                 \
                bf16x8 vf = *(const bf16x8*)                                 \
                    &Vlds[vprv][(ct*4 + kc)*512 + lane*8];                   \
                accO[ct] = __builtin_amdgcn_mfma_f32_32x32x16_bf16(          \
                               pa_prev[kc], vf, accO[ct], 0, 0, 0);          \
            }                                                                \
        __builtin_amdgcn_s_setprio(0);                                       \
    }                                                                        \
    /* softmax(T64): 32 scores/lane + defer-max */                           \
    float mx = -1e30f;                                                       \
    _Pragma("unroll")                                                        \
    for (int kt = 0; kt < 2; ++kt)                                           \
        _Pragma("unroll")                                                    \
        for (int r = 0; r < 16; ++r) mx = fmaxf(mx, accS[kt][r]);            \
    mx = fmaxf(mx, __shfl_xor(mx, 32));                                      \
    bool skip = __all(mx <= mrow + 8.f) != 0;                                \
    float mnew  = skip ? mrow : fmaxf(mrow, mx);                             \
    float alpha = __expf(mrow - mnew);                                       \
    mrow = mnew;                                                             \
    float p_[2][16];                                                         \
    float rs = 0.f;                                                          \
    _Pragma("unroll")                                                        \
    for (int kt = 0; kt < 2; ++kt)                                           \
        _Pragma("unroll")                                                    \
        for (int r = 0; r < 16; ++r) {                                       \
            float e_ = __expf(accS[kt][r] - mnew);                           \
            p_[kt][r] = e_;                                                  \
            rs += e_;                                                        \
        }                                                                    \
    rs += __shfl_xor(rs, 32);                                                \
    lrow = lrow * alpha + rs;                                                \
    if (!skip && h == 0) AL[w][q32] = alpha;                                 \
    skip_prev = skip;                                                        \
    /* P -> PV A-frags in register (verified R8 mapping) */                  \
    _Pragma("unroll")                                                        \
    for (int kt = 0; kt < 2; ++kt)                                           \
        _Pragma("unroll")                                                    \
        for (int cp = 0; cp < 2; ++cp) {                                     \
            unsigned int Y0 = cvt_pk_bf16(p_[kt][8*cp + 0], p_[kt][8*cp + 1]);\
            unsigned int Y1 = cvt_pk_bf16(p_[kt][8*cp + 2], p_[kt][8*cp + 3]);\
            unsigned int X0 = cvt_pk_bf16(p_[kt][8*cp + 4], p_[kt][8*cp + 5]);\
            unsigned int X1 = cvt_pk_bf16(p_[kt][8*cp + 6], p_[kt][8*cp + 7]);\
            asm volatile("v_permlane32_swap_b32 %0, %1" : "+v"(Y0), "+v"(X0));\
            asm volatile("v_permlane32_swap_b32 %0, %1" : "+v"(Y1), "+v"(X1));\
            uint4 fu; fu.x = Y0; fu.y = Y1; fu.z = X0; fu.w = X1;            \
            pa_prev[kt*2 + cp] = __builtin_bit_cast(bf16x8, fu);             \
        }                                                                    \
    __syncthreads();  /* drains prefetch DMA; fences buffer rotation */      \
    vprv = vcur; vcur = vnxt; vnxt = (vnxt + 1 == 3) ? 0 : vnxt + 1;         \
    kcur ^= 1;                                                               \
} while (0)

    // prologue: stage tile cstart
    STAGE_K(cstart, 0);
    STAGE_V(cstart, 0);
    __syncthreads();

    int vcur = 0, vnxt = 1, vprv = 2, kcur = 0;

    FITER(cstart, 0, 1);                              // first: no PV yet
    for (int t64 = cstart + 1; t64 < cend - 1; ++t64)
        FITER(t64, 1, 1);                             // 14 steady iterations
    FITER(cend - 1, 1, 0);                            // last: no prefetch

    // epilogue: PV(cend-1)
    if (!skip_prev) {
        float4 av_[4];
#pragma unroll
        for (int gp_ = 0; gp_ < 4; ++gp_)
            av_[gp_] = *(const float4*)&AL[w][8*gp_ + 4*h];
#pragma unroll
        for (int ct = 0; ct < 8; ++ct)
#pragma unroll
            for (int gp_ = 0; gp_ < 4; ++gp_)
#pragma unroll
                for (int i_ = 0; i_ < 4; ++i_)
                    accO[ct][4*gp_ + i_] *= av_[gp_][i_];
    }
#pragma unroll
    for (int ct = 0; ct < 8; ++ct)
#pragma unroll
        for (int kc = 0; kc < 4; ++kc) {
            bf16x8 vf = *(const bf16x8*)
                &Vlds[vprv][(ct*4 + kc)*512 + lane*8];
            accO[ct] = __builtin_amdgcn_mfma_f32_32x32x16_bf16(
                           pa_prev[kc], vf, accO[ct], 0, 0, 0);
        }

    // store unnormalized partial O (bf16) + per-query m,l
    const size_t tbase = ((size_t)(quarter*B_ + b)*16 + tile);
    unsigned short* Ob = Opart + tbase * (C_ * 256);
    float* ml = ML + tbase * 512;

    if (h == 0) {
        ml[32*w + q32]       = mrow;
        ml[256 + 32*w + q32] = lrow;
    }

#pragma unroll
    for (int ct = 0; ct < 8; ++ct) {
        int c = 32*ct + q32;
#pragma unroll
        for (int gp = 0; gp < 4; ++gp) {
            uint2 pu;
            pu.x = cvt_pk_bf16(accO[ct][4*gp + 0], accO[ct][4*gp + 1]);
            pu.y = cvt_pk_bf16(accO[ct][4*gp + 2], accO[ct][4*gp + 3]);
            *(uint2*)(Ob + (size_t)c*256 + 32*w + 8*gp + 4*h) = pu;
        }
    }
#undef FITER
#undef STAGE_K
#undef STAGE_V
}

// ---------------------------------------------------------------------------
// Combine: S=4 static, 256-query tiles, 32 channels per block (R8 verbatim).
// ---------------------------------------------------------------------------
__global__ __launch_bounds__(256) void combine_kernel(
    const unsigned short* __restrict__ Opart, const float* __restrict__ ML,
    const float* __restrict__ x, const float* __restrict__ gamma,
    float* __restrict__ out)
{
    __shared__ float sc[4][256];
    const int tile   = blockIdx.x;      // 0..15
    const int cslice = blockIdx.y;      // 0..7
    const int b      = blockIdx.z;
    const int n0     = tile * 256;
    const int t      = threadIdx.x;     // 0..255 (= query for phase 1)

    {
        float mm[4], ll[4];
        float M = -1e30f;
#pragma unroll
        for (int s = 0; s < 4; ++s) {
            const float* mls = ML + ((size_t)(s*B_ + b)*16 + tile)*512;
            mm[s] = mls[t];
            ll[s] = mls[256 + t];
            M = fmaxf(M, mm[s]);
        }
        float fs[4];
        float L = 0.f;
#pragma unroll
        for (int s = 0; s < 4; ++s) { fs[s] = __expf(mm[s] - M); L += fs[s]*ll[s]; }
        float gm = gamma[0];
#pragma unroll
        for (int s = 0; s < 4; ++s) sc[s][t] = gm * fs[s] / L;
    }
    __syncthreads();

    const int nq = t & 63;              // query-quad (float4 column)
    const int cl = t >> 6;              // 0..3
    const float* xb = x   + (size_t)b*C_*N_;
    float*       ob = out + (size_t)b*C_*N_;
    const unsigned short* Os[4];
#pragma unroll
    for (int s = 0; s < 4; ++s)
        Os[s] = Opart + ((size_t)(s*B_ + b)*16 + tile)*(C_*256);

    float sv[4][4];
#pragma unroll
    for (int s = 0; s < 4; ++s)
#pragma unroll
        for (int k = 0; k < 4; ++k) sv[s][k] = sc[s][4*nq + k];

#pragma unroll
    for (int i = 0; i < 8; ++i) {
        int c = 32*cslice + 4*i + cl;
        float4 x4 = *(const float4*)(xb + (size_t)c*N_ + n0 + 4*nq);
        float4 y = x4;
#pragma unroll
        for (int s = 0; s < 4; ++s) {
            ushort4v a4 = *(const ushort4v*)(Os[s] + (size_t)c*256 + 4*nq);
            y.x += sv[s][0]*bf2f(a4[0]);
            y.y += sv[s][1]*bf2f(a4[1]);
            y.z += sv[s][2]*bf2f(a4[2]);
            y.w += sv[s][3]*bf2f(a4[3]);
        }
        *(float4*)(ob + (size_t)c*N_ + n0 + 4*nq) = y;
    }
}

// ---------------------------------------------------------------------------
extern "C" void kernel_launch(void* const* d_in, const int* in_sizes, int n_in,
                              void* d_out, int out_size, void* d_ws, size_t ws_size,
                              hipStream_t stream) {
    const float* x     = (const float*)d_in[0];
    const float* Wq    = (const float*)d_in[1];
    const float* bq    = (const float*)d_in[2];
    const float* Wk    = (const float*)d_in[3];
    const float* bk    = (const float*)d_in[4];
    const float* Wv    = (const float*)d_in[5];
    const float* bv    = (const float*)d_in[6];
    const float* gamma = (const float*)d_in[7];
    float* out = (float*)d_out;

    // ws layout (~46.1 MB):
    unsigned short* Qg = (unsigned short*)d_ws;            // 2 MiB
    unsigned short* Kg = Qg + (size_t)B_*N_*D_;            // 2 MiB
    unsigned short* Vg = Kg + (size_t)B_*N_*D_;            // 8 MiB
    unsigned short* Op = Vg + (size_t)B_*C_*N_;            // 33.6 MiB (S=4)
    float* ML = (float*)(Op + (size_t)4*B_*16*C_*256);     // 512 KiB

    proj_kernel<<<dim3(64, 3, 4), 256, 0, stream>>>(x, Wq, Wk, Wv,
                                                    bq, bk, bv, Qg, Kg, Vg);
    flash_kernel<<<dim3(16, 16), 512, 0, stream>>>(Qg, Kg, Vg, Op, ML);
    combine_kernel<<<dim3(16, 8, 4), 256, 0, stream>>>(Op, ML, x, gamma, out);
}

// Round 10
// 162.266 us; speedup vs baseline: 1.6027x; 1.0458x over previous
//
#include <hip/hip_runtime.h>

#define B_ 4
#define C_ 256
#define N_ 4096
#define D_ 64

typedef __bf16 bf16x8 __attribute__((ext_vector_type(8)));
typedef float floatx4 __attribute__((ext_vector_type(4)));
typedef float floatx16 __attribute__((ext_vector_type(16)));
typedef unsigned short ushort8v __attribute__((ext_vector_type(8)));
typedef unsigned short ushort4v __attribute__((ext_vector_type(4)));
typedef unsigned short ushort2v __attribute__((ext_vector_type(2)));

static __device__ __forceinline__ unsigned short f2bf(float f) {
    unsigned int u = __builtin_bit_cast(unsigned int, f);
    u += 0x7fffu + ((u >> 16) & 1u);   // RNE
    return (unsigned short)(u >> 16);
}
static __device__ __forceinline__ float bf2f(unsigned short h) {
    unsigned int u = ((unsigned int)h) << 16;
    return __builtin_bit_cast(float, u);
}
// HW packed f32x2 -> bf16x2 (RNE), 1 VALU op; src0 -> low half
static __device__ __forceinline__ unsigned int cvt_pk_bf16(float lo, float hi) {
    unsigned int d;
    asm("v_cvt_pk_bf16_f32 %0, %1, %2" : "=v"(d) : "v"(lo), "v"(hi));
    return d;
}

// async global->LDS DMA, 16B/lane, dst = wave-uniform base + lane*16,
// src = PER-LANE global address (enables transposed staging).
#define GLOAD16(gp, lp)                                                      \
    __builtin_amdgcn_global_load_lds(                                        \
        (const __attribute__((address_space(1))) void*)(gp),                 \
        (__attribute__((address_space(3))) void*)(lp), 16, 0, 0)

// ---------------------------------------------------------------------------
// One-time W conversion into A-frag-native layout (R5 verbatim, verified):
//   WbfA[((ft*8 + ks)*64 + lane)*8 + j] = W[16*ft + (lane&15)]
//                                          [32*ks + 8*(lane>>4) + j]
// so proj's A-frag load is wave-uniform base + lane*16B (coalesced 1 KB).
// ---------------------------------------------------------------------------
__global__ __launch_bounds__(256) void convert_w(
    const float* __restrict__ Wq, const float* __restrict__ Wk,
    const float* __restrict__ Wv, unsigned short* __restrict__ WbfA)
{
    int tid = blockIdx.x * 256 + threadIdx.x;   // 0..24575
    int p0  = tid * 4;                          // output short index
    int j0   = p0 & 7;
    int lane = (p0 >> 3) & 63;
    int sidx = p0 >> 9;
    int ft = sidx >> 3, ks = sidx & 7;
    int m  = lane & 15, g = lane >> 4;
    int f  = 16*ft + m;
    int c  = 32*ks + 8*g + j0;
    const float* src = (f < 64)  ? (Wq + (size_t)f * C_)
                     : (f < 128) ? (Wk + (size_t)(f - 64) * C_)
                                 : (Wv + (size_t)(f - 128) * C_);
    float4 v = *(const float4*)(src + c);
    uint2 u;
    u.x = cvt_pk_bf16(v.x, v.y);
    u.y = cvt_pk_bf16(v.z, v.w);
    *(uint2*)(WbfA + p0) = u;
}

// ---------------------------------------------------------------------------
// MFMA projection (R5 body: coalesced WbfA A-frag loads) + vectorized Q/K
// gather (8x ds_read_b64 + in-reg 8x4 transpose, replaces 32 scalar
// ds_read_u16) + 4 blocks/CU.
// ---------------------------------------------------------------------------
__global__ __launch_bounds__(256, 4) void proj_kernel(
    const float* __restrict__ x, const unsigned short* __restrict__ WbfA,
    const float* __restrict__ bq, const float* __restrict__ bk,
    const float* __restrict__ bv,
    unsigned short* __restrict__ Qg, unsigned short* __restrict__ Kg,
    unsigned short* __restrict__ Vg)
{
    __shared__ __align__(16) unsigned short smem[64 * 264];  // 33792 B
    unsigned short* xs = smem;          // x tile, swizzled [n][264]
    unsigned short* Lt = smem;          // epilogue tile [128][72] (union)

    const int n0 = blockIdx.x * 64;
    const int f0 = blockIdx.y * 128;
    const int b  = blockIdx.z;
    const int t  = threadIdx.x;
    const int w  = t >> 6;
    const int lane = t & 63;
    const int g  = lane >> 4;
    const int m  = lane & 15;

    // ---- stage x tile -> LDS bf16, swizzled ----
#pragma unroll
    for (int k = 0; k < 8; ++k) {
        int e  = t + 256 * k;           // 0..2047
        int cp = e >> 4;                // 0..127
        int c  = 2 * cp;
        int n4 = (e & 15) * 4;
        float4 v0 = *(const float4*)(x + ((size_t)b*C_ + c    )*N_ + n0 + n4);
        float4 v1 = *(const float4*)(x + ((size_t)b*C_ + c + 1)*N_ + n0 + n4);
        float a0[4] = {v0.x, v0.y, v0.z, v0.w};
        float a1[4] = {v1.x, v1.y, v1.z, v1.w};
#pragma unroll
        for (int j = 0; j < 4; ++j) {
            int n = n4 + j;
            unsigned int u = cvt_pk_bf16(a0[j], a1[j]);
            *(unsigned int*)&xs[n*264 + (((c >> 3) ^ (n & 7)) << 3) + (c & 7)] = u;
        }
    }

    float bias_[2][4];
#pragma unroll
    for (int mt = 0; mt < 2; ++mt)
#pragma unroll
        for (int r = 0; r < 4; ++r) {
            int fg = f0 + 32*w + 16*mt + 4*g + r;
            bias_[mt][r] = (fg < 64) ? bq[fg]
                         : (fg < 128) ? bk[fg - 64] : bv[fg - 128];
        }

    // A-frag segment bases (coalesced, L2-hot)
    const unsigned short* Wa0 = WbfA + (size_t)(((f0 >> 4) + 2*w    )*8)*512
                              + lane*8;
    const unsigned short* Wa1 = WbfA + (size_t)(((f0 >> 4) + 2*w + 1)*8)*512
                              + lane*8;

    floatx4 acc[2][4];
#pragma unroll
    for (int mt = 0; mt < 2; ++mt)
#pragma unroll
        for (int nt = 0; nt < 4; ++nt) acc[mt][nt] = (floatx4){0.f,0.f,0.f,0.f};

    __syncthreads();   // x tile staged

#pragma unroll
    for (int ks = 0; ks < 8; ++ks) {
        bf16x8 af[2];
        af[0] = *(const bf16x8*)(Wa0 + ks*512);
        af[1] = *(const bf16x8*)(Wa1 + ks*512);
#pragma unroll
        for (int nt = 0; nt < 4; ++nt) {
            int n = 16*nt + m;
            bf16x8 bfr = *(const bf16x8*)
                &xs[n*264 + (((4*ks + g) ^ (n & 7)) << 3)];
#pragma unroll
            for (int mt = 0; mt < 2; ++mt)
                acc[mt][nt] = __builtin_amdgcn_mfma_f32_16x16x32_bf16(
                                  af[mt], bfr, acc[mt][nt], 0, 0, 0);
        }
    }

    __syncthreads();   // xs dead -> Lt overlay

#pragma unroll
    for (int mt = 0; mt < 2; ++mt)
#pragma unroll
        for (int nt = 0; nt < 4; ++nt)
#pragma unroll
            for (int r = 0; r < 4; ++r)
                Lt[(32*w + 16*mt + 4*g + r)*72 + 16*nt + m] =
                    f2bf(acc[mt][nt][r] + bias_[mt][r]);
    __syncthreads();

    if (f0 == 0) {
        // vectorized transpose gather: 8x ds_read_b64 (conflict-free) +
        // in-register 8x4 transpose + 4 coalesced ushort8 stores.
        const int fq0 = (t >> 4) * 8;       // 0,8,...,120
        const int nl4 = (t & 15) * 4;       // 0,4,...,60
        ushort4v col[8];
#pragma unroll
        for (int j = 0; j < 8; ++j)
            col[j] = *(const ushort4v*)&Lt[(fq0 + j)*72 + nl4];
#pragma unroll
        for (int c = 0; c < 4; ++c) {
            ushort8v u;
#pragma unroll
            for (int j = 0; j < 8; ++j) u[j] = col[j][c];
            int nl = nl4 + c;
            unsigned short* dst = (fq0 < 64)
                ? (Qg + ((size_t)b*N_ + n0 + nl)*D_ + fq0)
                : (Kg + ((size_t)b*N_ + n0 + nl)*D_ + (fq0 - 64));
            *(ushort8v*)dst = u;
        }
    } else {
        const int cb = f0 - 128;
#pragma unroll
        for (int k = 0; k < 4; ++k) {
            int e  = t + 256 * k;
            int fr = e >> 3;
            int n8 = (e & 7) * 8;
            ushort8v u = *(const ushort8v*)&Lt[fr*72 + n8];
            *(ushort8v*)(Vg + ((size_t)b*C_ + cb + fr)*N_ + n0 + n8) = u;
        }
    }
}

// ---------------------------------------------------------------------------
// Flash attention 32x32x16 + one-tile-lag PV pipeline + defer-max
// (R9 verbatim — 69.8 us measured, PASSED).
// ---------------------------------------------------------------------------
__global__ __launch_bounds__(512, 2) void flash_kernel(
    const unsigned short* __restrict__ Qg, const unsigned short* __restrict__ Kg,
    const unsigned short* __restrict__ Vg,
    unsigned short* __restrict__ Opart, float* __restrict__ ML)
{
    __shared__ __align__(16) unsigned short Vlds[3][32 * 512];  // 96 KB
    __shared__ __align__(16) unsigned short Klds[2][8 * 512];   // 16 KB
    __shared__ float AL[8][32];                                 //  1 KB

    const int gx   = blockIdx.x;        // quarter + 4*b (XCD pin: gx%8)
    const int tile = blockIdx.y;        // 0..15 (256-query tiles)
    const int quarter = gx & 3;
    const int b    = gx >> 2;
    const int n0   = tile * 256;
    const int t    = threadIdx.x;
    const int w    = t >> 6;            // 0..7
    const int lane = t & 63;
    const int q32  = lane & 31;         // query within wave / col index
    const int h    = lane >> 5;         // lane half

    const unsigned short* Qb = Qg + ((size_t)b*N_ + n0)*D_;
    const unsigned short* Kb = Kg + (size_t)b*N_*D_;
    const unsigned short* Vb = Vg + (size_t)b*C_*N_;

    const int cstart = quarter * 16;
    const int cend   = cstart + 16;

    // Q B-frags (stationary): col=q32, k=8h+j per 16-chunk ks
    bf16x8 qf[4];
#pragma unroll
    for (int ks = 0; ks < 4; ++ks)
        qf[ks] = *(const bf16x8*)(Qb + (size_t)(32*w + q32)*D_ + 16*ks + 8*h);

    floatx16 accO[8];
#pragma unroll
    for (int ct = 0; ct < 8; ++ct)
#pragma unroll
        for (int r = 0; r < 16; ++r) accO[ct][r] = 0.f;

    float mrow = -1e30f, lrow = 0.f;
    bf16x8 pa_prev[4];
    bool skip_prev = true;              // no pending PV before first iter

#define STAGE_K(T64, BUF) do {                                               \
    const unsigned short* gp = Kb                                            \
        + (size_t)((T64)*64 + 32*(w >> 2) + q32)*D_ + 16*(w & 3) + 8*h;      \
    GLOAD16(gp, &Klds[BUF][w * 512]); } while (0)

#define STAGE_V(T64, BUF) do {                                               \
    _Pragma("unroll")                                                        \
    for (int u_ = 0; u_ < 4; ++u_) {                                         \
        const unsigned short* gp = Vb                                        \
            + (size_t)(32*w + q32)*N_ + (T64)*64 + 16*u_ + 8*h;              \
        GLOAD16(gp, &Vlds[BUF][(w*4 + u_) * 512]);                           \
    } } while (0)

#define FITER(T64, HASPV, HASPRE) do {                                       \
    if (HASPRE) { STAGE_K((T64)+1, kcur ^ 1); STAGE_V((T64)+1, vnxt); }      \
    /* ST(T64) = K*Q */                                                      \
    floatx16 accS[2];                                                        \
    _Pragma("unroll")                                                        \
    for (int kt = 0; kt < 2; ++kt)                                           \
        _Pragma("unroll")                                                    \
        for (int r = 0; r < 16; ++r) accS[kt][r] = 0.f;                      \
    _Pragma("unroll")                                                        \
    for (int kt = 0; kt < 2; ++kt)                                           \
        _Pragma("unroll")                                                    \
        for (int ks = 0; ks < 4; ++ks) {                                     \
            bf16x8 kfr = *(const bf16x8*)                                    \
                &Klds[kcur][(kt*4 + ks)*512 + lane*8];                       \
            accS[kt] = __builtin_amdgcn_mfma_f32_32x32x16_bf16(              \
                           kfr, qf[ks], accS[kt], 0, 0, 0);                  \
        }                                                                    \
    /* PV(T64-1): independent of softmax below -> overlaps it */             \
    if (HASPV) {                                                             \
        if (!skip_prev) {                                                    \
            float4 av_[4];                                                   \
            _Pragma("unroll")                                                \
            for (int gp_ = 0; gp_ < 4; ++gp_)                                \
                av_[gp_] = *(const float4*)&AL[w][8*gp_ + 4*h];              \
            _Pragma("unroll")                                                \
            for (int ct = 0; ct < 8; ++ct)                                   \
                _Pragma("unroll")                                            \
                for (int gp_ = 0; gp_ < 4; ++gp_)                            \
                    _Pragma("unroll")                                        \
                    for (int i_ = 0; i_ < 4; ++i_)                           \
                        accO[ct][4*gp_ + i_] *= av_[gp_][i_];                \
        }                                                                    \
        __builtin_amdgcn_s_setprio(1);                                       \
        _Pragma("unroll")                                                    \
        for (int ct = 0; ct < 8; ++ct)                                       \
            _Pragma("unroll")                                                \
            for (int kc = 0; kc < 4; ++kc) {                                 \
                bf16x8 vf = *(const bf16x8*)                                 \
                    &Vlds[vprv][(ct*4 + kc)*512 + lane*8];                   \
                accO[ct] = __builtin_amdgcn_mfma_f32_32x32x16_bf16(          \
                               pa_prev[kc], vf, accO[ct], 0, 0, 0);          \
            }                                                                \
        __builtin_amdgcn_s_setprio(0);                                       \
    }                                                                        \
    /* softmax(T64): 32 scores/lane + defer-max */                           \
    float mx = -1e30f;                                                       \
    _Pragma("unroll")                                                        \
    for (int kt = 0; kt < 2; ++kt)                                           \
        _Pragma("unroll")                                                    \
        for (int r = 0; r < 16; ++r) mx = fmaxf(mx, accS[kt][r]);            \
    mx = fmaxf(mx, __shfl_xor(mx, 32));                                      \
    bool skip = __all(mx <= mrow + 8.f) != 0;                                \
    float mnew  = skip ? mrow : fmaxf(mrow, mx);                             \
    float alpha = __expf(mrow - mnew);                                       \
    mrow = mnew;                                                             \
    float p_[2][16];                                                         \
    float rs = 0.f;                                                          \
    _Pragma("unroll")                                                        \
    for (int kt = 0; kt < 2; ++kt)                                           \
        _Pragma("unroll")                                                    \
        for (int r = 0; r < 16; ++r) {                                       \
            float e_ = __expf(accS[kt][r] - mnew);                           \
            p_[kt][r] = e_;                                                  \
            rs += e_;                                                        \
        }                                                                    \
    rs += __shfl_xor(rs, 32);                                                \
    lrow = lrow * alpha + rs;                                                \
    if (!skip && h == 0) AL[w][q32] = alpha;                                 \
    skip_prev = skip;                                                        \
    /* P -> PV A-frags in register (verified R8 mapping) */                  \
    _Pragma("unroll")                                                        \
    for (int kt = 0; kt < 2; ++kt)                                           \
        _Pragma("unroll")                                                    \
        for (int cp = 0; cp < 2; ++cp) {                                     \
            unsigned int Y0 = cvt_pk_bf16(p_[kt][8*cp + 0], p_[kt][8*cp + 1]);\
            unsigned int Y1 = cvt_pk_bf16(p_[kt][8*cp + 2], p_[kt][8*cp + 3]);\
            unsigned int X0 = cvt_pk_bf16(p_[kt][8*cp + 4], p_[kt][8*cp + 5]);\
            unsigned int X1 = cvt_pk_bf16(p_[kt][8*cp + 6], p_[kt][8*cp + 7]);\
            asm volatile("v_permlane32_swap_b32 %0, %1" : "+v"(Y0), "+v"(X0));\
            asm volatile("v_permlane32_swap_b32 %0, %1" : "+v"(Y1), "+v"(X1));\
            uint4 fu; fu.x = Y0; fu.y = Y1; fu.z = X0; fu.w = X1;            \
            pa_prev[kt*2 + cp] = __builtin_bit_cast(bf16x8, fu);             \
        }                                                                    \
    __syncthreads();  /* drains prefetch DMA; fences buffer rotation */      \
    vprv = vcur; vcur = vnxt; vnxt = (vnxt + 1 == 3) ? 0 : vnxt + 1;         \
    kcur ^= 1;                                                               \
} while (0)

    // prologue: stage tile cstart
    STAGE_K(cstart, 0);
    STAGE_V(cstart, 0);
    __syncthreads();

    int vcur = 0, vnxt = 1, vprv = 2, kcur = 0;

    FITER(cstart, 0, 1);                              // first: no PV yet
    for (int t64 = cstart + 1; t64 < cend - 1; ++t64)
        FITER(t64, 1, 1);                             // 14 steady iterations
    FITER(cend - 1, 1, 0);                            // last: no prefetch

    // epilogue: PV(cend-1)
    if (!skip_prev) {
        float4 av_[4];
#pragma unroll
        for (int gp_ = 0; gp_ < 4; ++gp_)
            av_[gp_] = *(const float4*)&AL[w][8*gp_ + 4*h];
#pragma unroll
        for (int ct = 0; ct < 8; ++ct)
#pragma unroll
            for (int gp_ = 0; gp_ < 4; ++gp_)
#pragma unroll
                for (int i_ = 0; i_ < 4; ++i_)
                    accO[ct][4*gp_ + i_] *= av_[gp_][i_];
    }
#pragma unroll
    for (int ct = 0; ct < 8; ++ct)
#pragma unroll
        for (int kc = 0; kc < 4; ++kc) {
            bf16x8 vf = *(const bf16x8*)
                &Vlds[vprv][(ct*4 + kc)*512 + lane*8];
            accO[ct] = __builtin_amdgcn_mfma_f32_32x32x16_bf16(
                           pa_prev[kc], vf, accO[ct], 0, 0, 0);
        }

    // store unnormalized partial O (bf16) + per-query m,l
    const size_t tbase = ((size_t)(quarter*B_ + b)*16 + tile);
    unsigned short* Ob = Opart + tbase * (C_ * 256);
    float* ml = ML + tbase * 512;

    if (h == 0) {
        ml[32*w + q32]       = mrow;
        ml[256 + 32*w + q32] = lrow;
    }

#pragma unroll
    for (int ct = 0; ct < 8; ++ct) {
        int c = 32*ct + q32;
#pragma unroll
        for (int gp = 0; gp < 4; ++gp) {
            uint2 pu;
            pu.x = cvt_pk_bf16(accO[ct][4*gp + 0], accO[ct][4*gp + 1]);
            pu.y = cvt_pk_bf16(accO[ct][4*gp + 2], accO[ct][4*gp + 3]);
            *(uint2*)(Ob + (size_t)c*256 + 32*w + 8*gp + 4*h) = pu;
        }
    }
#undef FITER
#undef STAGE_K
#undef STAGE_V
}

// ---------------------------------------------------------------------------
// Combine: S=4 static, 256-query tiles, 32 channels per block (R8 verbatim).
// ---------------------------------------------------------------------------
__global__ __launch_bounds__(256) void combine_kernel(
    const unsigned short* __restrict__ Opart, const float* __restrict__ ML,
    const float* __restrict__ x, const float* __restrict__ gamma,
    float* __restrict__ out)
{
    __shared__ float sc[4][256];
    const int tile   = blockIdx.x;      // 0..15
    const int cslice = blockIdx.y;      // 0..7
    const int b      = blockIdx.z;
    const int n0     = tile * 256;
    const int t      = threadIdx.x;     // 0..255 (= query for phase 1)

    {
        float mm[4], ll[4];
        float M = -1e30f;
#pragma unroll
        for (int s = 0; s < 4; ++s) {
            const float* mls = ML + ((size_t)(s*B_ + b)*16 + tile)*512;
            mm[s] = mls[t];
            ll[s] = mls[256 + t];
            M = fmaxf(M, mm[s]);
        }
        float fs[4];
        float L = 0.f;
#pragma unroll
        for (int s = 0; s < 4; ++s) { fs[s] = __expf(mm[s] - M); L += fs[s]*ll[s]; }
        float gm = gamma[0];
#pragma unroll
        for (int s = 0; s < 4; ++s) sc[s][t] = gm * fs[s] / L;
    }
    __syncthreads();

    const int nq = t & 63;              // query-quad (float4 column)
    const int cl = t >> 6;              // 0..3
    const float* xb = x   + (size_t)b*C_*N_;
    float*       ob = out + (size_t)b*C_*N_;
    const unsigned short* Os[4];
#pragma unroll
    for (int s = 0; s < 4; ++s)
        Os[s] = Opart + ((size_t)(s*B_ + b)*16 + tile)*(C_*256);

    float sv[4][4];
#pragma unroll
    for (int s = 0; s < 4; ++s)
#pragma unroll
        for (int k = 0; k < 4; ++k) sv[s][k] = sc[s][4*nq + k];

#pragma unroll
    for (int i = 0; i < 8; ++i) {
        int c = 32*cslice + 4*i + cl;
        float4 x4 = *(const float4*)(xb + (size_t)c*N_ + n0 + 4*nq);
        float4 y = x4;
#pragma unroll
        for (int s = 0; s < 4; ++s) {
            ushort4v a4 = *(const ushort4v*)(Os[s] + (size_t)c*256 + 4*nq);
            y.x += sv[s][0]*bf2f(a4[0]);
            y.y += sv[s][1]*bf2f(a4[1]);
            y.z += sv[s][2]*bf2f(a4[2]);
            y.w += sv[s][3]*bf2f(a4[3]);
        }
        *(float4*)(ob + (size_t)c*N_ + n0 + 4*nq) = y;
    }
}

// ---------------------------------------------------------------------------
extern "C" void kernel_launch(void* const* d_in, const int* in_sizes, int n_in,
                              void* d_out, int out_size, void* d_ws, size_t ws_size,
                              hipStream_t stream) {
    const float* x     = (const float*)d_in[0];
    const float* Wq    = (const float*)d_in[1];
    const float* bq    = (const float*)d_in[2];
    const float* Wk    = (const float*)d_in[3];
    const float* bk    = (const float*)d_in[4];
    const float* Wv    = (const float*)d_in[5];
    const float* bv    = (const float*)d_in[6];
    const float* gamma = (const float*)d_in[7];
    float* out = (float*)d_out;

    // ws layout (~46.3 MB):
    unsigned short* Qg = (unsigned short*)d_ws;            // 2 MiB
    unsigned short* Kg = Qg + (size_t)B_*N_*D_;            // 2 MiB
    unsigned short* Vg = Kg + (size_t)B_*N_*D_;            // 8 MiB
    unsigned short* Op = Vg + (size_t)B_*C_*N_;            // 33.6 MiB (S=4)
    float* ML = (float*)(Op + (size_t)4*B_*16*C_*256);     // 512 KiB
    unsigned short* WbfA = (unsigned short*)(ML + (size_t)4*B_*16*512); // 192 KiB

    convert_w<<<dim3(96), 256, 0, stream>>>(Wq, Wk, Wv, WbfA);
    proj_kernel<<<dim3(64, 3, 4), 256, 0, stream>>>(x, WbfA, bq, bk, bv,
                                                    Qg, Kg, Vg);
    flash_kernel<<<dim3(16, 16), 512, 0, stream>>>(Qg, Kg, Vg, Op, ML);
    combine_kernel<<<dim3(16, 8, 4), 256, 0, stream>>>(Op, ML, x, gamma, out);
}